// Round 1
// baseline (1918.182 us; speedup 1.0000x reference)
//
#include <hip/hip_runtime.h>

#define NN 100000
#define NE 1600000
#define NG 512
#define FIN 226
#define HD 128
#define BN_EPS 1e-5f

// ---------------- CSR build ----------------
__global__ void k_hist(const int* __restrict__ dst, int* __restrict__ counts) {
  int e = blockIdx.x * 256 + threadIdx.x;
  if (e < NE) atomicAdd(&counts[dst[e]], 1);
}

__global__ __launch_bounds__(1024) void k_scan(const int* __restrict__ counts,
                                               int* __restrict__ row_ptr) {
  __shared__ int wtot[16];
  __shared__ int woff[16];
  __shared__ int carry;
  const int tid = threadIdx.x;
  const int lane = tid & 63, wid = tid >> 6;
  if (tid == 0) { carry = 0; row_ptr[0] = 0; }
  __syncthreads();
  for (int base = 0; base < NN; base += 1024) {
    int i = base + tid;
    int v = (i < NN) ? counts[i] : 0;
    int incl = v;
    #pragma unroll
    for (int off = 1; off < 64; off <<= 1) {
      int u = __shfl_up(incl, off);
      if (lane >= off) incl += u;
    }
    if (lane == 63) wtot[wid] = incl;
    __syncthreads();
    if (tid == 0) {
      int run = carry;
      #pragma unroll
      for (int w = 0; w < 16; ++w) { woff[w] = run; run += wtot[w]; }
      carry = run;
    }
    __syncthreads();
    if (i < NN) row_ptr[i + 1] = woff[wid] + incl;
  }
}

__global__ void k_fill(const int* __restrict__ src, const int* __restrict__ dst,
                       const int* __restrict__ row_ptr, int* __restrict__ cursor,
                       int* __restrict__ col_idx) {
  int e = blockIdx.x * 256 + threadIdx.x;
  if (e < NE) {
    int d = dst[e];
    int pos = row_ptr[d] + atomicAdd(&cursor[d], 1);
    col_idx[pos] = src[e];
  }
}

// ---------------- BN fold ----------------
__global__ void k_prefold(const float* __restrict__ Wa, const float* __restrict__ ba,
                          const float* __restrict__ g, const float* __restrict__ be,
                          const float* __restrict__ rm, const float* __restrict__ rv,
                          float* __restrict__ Wout, float* __restrict__ bout, int K) {
  int id = blockIdx.x * 256 + threadIdx.x;
  if (id >= K * HD) return;
  int c = id & (HD - 1);
  float s = g[c] * rsqrtf(rv[c] + BN_EPS);
  Wout[id] = Wa[id] * s;
  if (id < HD) bout[id] = ba[id] * s + be[id] - rm[id] * s;
}

// ---------------- fp32 GEMM: [M x K] @ [K x 128] ----------------
// block: 256 threads, tile 32 rows x 128 cols, 4x4 register tile per thread
template <int BIAS, int RELU>
__global__ __launch_bounds__(256) void k_gemm(const float* __restrict__ A,
                                              const float* __restrict__ W,
                                              const float* __restrict__ bias,
                                              float* __restrict__ out, int K) {
  __shared__ float AsT[32][36];    // A transposed [kk][m], pad to 36 (16B-aligned rows)
  __shared__ float Ws[32 * 128];
  const int tid = threadIdx.x;
  const int m0 = blockIdx.x * 32;
  const int tc = (tid & 31) * 4;   // col 0..124
  const int tr = (tid >> 5) * 4;   // row 0..28
  const int arow = tid >> 3;       // 0..31
  const int ak = (tid & 7) * 4;    // 0..28
  float acc[4][4] = {};
  for (int k0 = 0; k0 < K; k0 += 32) {
    #pragma unroll
    for (int i = 0; i < 4; ++i) {
      int kk = ak + i;
      float v = 0.f;
      if (k0 + kk < K) v = A[(size_t)(m0 + arow) * K + k0 + kk];
      AsT[kk][arow] = v;
    }
    const int limit = (K - k0) * 128;
    #pragma unroll
    for (int i = 0; i < 16; ++i) {
      int idx = tid + 256 * i;
      Ws[idx] = (idx < limit) ? W[(size_t)k0 * 128 + idx] : 0.f;
    }
    __syncthreads();
    #pragma unroll
    for (int kk = 0; kk < 32; ++kk) {
      const float4 a4 = *reinterpret_cast<const float4*>(&AsT[kk][tr]);
      const float4 w4 = *reinterpret_cast<const float4*>(&Ws[kk * 128 + tc]);
      const float a[4] = {a4.x, a4.y, a4.z, a4.w};
      const float w[4] = {w4.x, w4.y, w4.z, w4.w};
      #pragma unroll
      for (int r = 0; r < 4; ++r)
        #pragma unroll
        for (int c = 0; c < 4; ++c)
          acc[r][c] = fmaf(a[r], w[c], acc[r][c]);
    }
    __syncthreads();
  }
  #pragma unroll
  for (int r = 0; r < 4; ++r) {
    float4 o = {acc[r][0], acc[r][1], acc[r][2], acc[r][3]};
    if (BIAS) {
      o.x += bias[tc]; o.y += bias[tc + 1]; o.z += bias[tc + 2]; o.w += bias[tc + 3];
    }
    if (RELU) {
      o.x = fmaxf(o.x, 0.f); o.y = fmaxf(o.y, 0.f);
      o.z = fmaxf(o.z, 0.f); o.w = fmaxf(o.w, 0.f);
    }
    *reinterpret_cast<float4*>(&out[(size_t)(m0 + tr + r) * HD + tc]) = o;
  }
}

// ---------------- aggregation: h[i] = relu(y[i] + sum_j y[j] + bias) ----------------
// one wave per node, lane covers 2 features (float2)
__global__ __launch_bounds__(256) void k_agg(const float* __restrict__ y,
                                             const int* __restrict__ row_ptr,
                                             const int* __restrict__ col_idx,
                                             const float* __restrict__ bias,
                                             float* __restrict__ h) {
  const int node = blockIdx.x * 4 + (threadIdx.x >> 6);
  const int lane = threadIdx.x & 63;
  if (node >= NN) return;
  const float2* y2 = reinterpret_cast<const float2*>(y);
  float2 acc = y2[(size_t)node * 64 + lane];
  const int beg = row_ptr[node], end = row_ptr[node + 1];
  for (int e = beg; e < end; ++e) {
    const int s = col_idx[e];
    const float2 v = y2[(size_t)s * 64 + lane];
    acc.x += v.x; acc.y += v.y;
  }
  const float2 b = reinterpret_cast<const float2*>(bias)[lane];
  float2 o;
  o.x = fmaxf(acc.x + b.x, 0.f);
  o.y = fmaxf(acc.y + b.y, 0.f);
  reinterpret_cast<float2*>(h)[(size_t)node * 64 + lane] = o;
}

// ---------------- pooling ----------------
__global__ __launch_bounds__(256) void k_pool(const float* __restrict__ h,
                                              const int* __restrict__ batch,
                                              const float* __restrict__ Wl,
                                              float* __restrict__ sums,
                                              float* __restrict__ cnts) {
  const int node = blockIdx.x * 4 + (threadIdx.x >> 6);
  const int lane = threadIdx.x & 63;
  if (node >= NN) return;
  const float2 hv = reinterpret_cast<const float2*>(h)[(size_t)node * 64 + lane];
  const float2 wv = reinterpret_cast<const float2*>(Wl)[lane];
  float d = hv.x * wv.x + hv.y * wv.y;
  #pragma unroll
  for (int off = 32; off > 0; off >>= 1) d += __shfl_down(d, off);
  if (lane == 0) {
    const int g = batch[node];
    atomicAdd(&sums[g], d);
    atomicAdd(&cnts[g], 1.f);
  }
}

__global__ void k_final(const float* __restrict__ sums, const float* __restrict__ cnts,
                        const float* __restrict__ bl, float* __restrict__ out) {
  int g = blockIdx.x * 256 + threadIdx.x;
  if (g < NG) out[g] = sums[g] / fmaxf(cnts[g], 1.f) + bl[0];
}

// ---------------- launch ----------------
extern "C" void kernel_launch(void* const* d_in, const int* in_sizes, int n_in,
                              void* d_out, int out_size, void* d_ws, size_t ws_size,
                              hipStream_t stream) {
  const float* x = (const float*)d_in[0];
  const int* edges = (const int*)d_in[1];
  const int* batch = (const int*)d_in[2];
  const int* e_src = edges;        // edge_index[0]
  const int* e_dst = edges + NE;   // edge_index[1]
  const float* Wl = (const float*)d_in[35];
  const float* bl = (const float*)d_in[36];
  float* out = (float*)d_out;
  auto P = [&](int l, int which) -> const float* {
    return (const float*)d_in[3 + (l - 1) * 8 + which];
  };
  // which: 0=Wa 1=ba 2=g 3=be 4=rm 5=rv 6=Wb 7=bb

  char* ws = (char*)d_ws;
  size_t off = 0;
  auto take = [&](size_t bytes) -> void* {
    void* p = ws + off;
    off = (off + bytes + 255) & ~(size_t)255;
    return p;
  };
  float* B0 = (float*)take((size_t)NN * HD * 4);          // 51.2 MB
  float* B1 = (float*)take((size_t)NN * HD * 4);          // 51.2 MB
  int* row_ptr = (int*)take((size_t)(NN + 1) * 4);
  int* cnt = (int*)take((size_t)NN * 4);                  // histogram, then cursor
  int* col_idx = (int*)take((size_t)NE * 4);
  float* Wf = (float*)take((size_t)(FIN + 3 * HD) * HD * 4);
  float* bf = (float*)take((size_t)4 * HD * 4);
  float* psum = (float*)take((size_t)NG * 4 * 2);         // sums then cnts
  float* pcnt = psum + NG;
  float* WfL[4] = {Wf, Wf + FIN * HD, Wf + (FIN + HD) * HD, Wf + (FIN + 2 * HD) * HD};

  // CSR build
  hipMemsetAsync(cnt, 0, (size_t)NN * 4, stream);
  k_hist<<<(NE + 255) / 256, 256, 0, stream>>>(e_dst, cnt);
  k_scan<<<1, 1024, 0, stream>>>(cnt, row_ptr);
  hipMemsetAsync(cnt, 0, (size_t)NN * 4, stream);
  k_fill<<<(NE + 255) / 256, 256, 0, stream>>>(e_src, e_dst, row_ptr, cnt, col_idx);

  // BN fold (scale Wa columns, fold bias)
  for (int l = 1; l <= 4; ++l) {
    int K = (l == 1) ? FIN : HD;
    k_prefold<<<(K * HD + 255) / 256, 256, 0, stream>>>(
        P(l, 0), P(l, 1), P(l, 2), P(l, 3), P(l, 4), P(l, 5), WfL[l - 1],
        bf + (l - 1) * HD, K);
  }

  hipMemsetAsync(psum, 0, (size_t)NG * 8, stream);

  // y1 = x @ W1a'
  k_gemm<0, 0><<<NN / 32, 256, 0, stream>>>(x, WfL[0], nullptr, B0, FIN);
  float* cur = B0;  // holds y_l
  float* alt = B1;
  for (int l = 1; l <= 4; ++l) {
    // h = relu(y + agg(y) + ba')
    k_agg<<<NN / 4, 256, 0, stream>>>(cur, row_ptr, col_idx, bf + (l - 1) * HD, alt);
    // x_next = relu(h @ Wb + bb)
    k_gemm<1, 1><<<NN / 32, 256, 0, stream>>>(alt, P(l, 6), P(l, 7), cur, HD);
    if (l < 4) {
      // y_{l+1} = x_next @ W(l+1)a'
      k_gemm<0, 0><<<NN / 32, 256, 0, stream>>>(cur, WfL[l], nullptr, alt, HD);
      float* t = cur; cur = alt; alt = t;
    }
  }
  // final node features in `cur` after last k_gemm<1,1> wrote into cur
  k_pool<<<NN / 4, 256, 0, stream>>>(cur, batch, Wl, psum, pcnt);
  k_final<<<(NG + 255) / 256, 256, 0, stream>>>(psum, pcnt, bl, out);
}

// Round 2
// 1187.981 us; speedup vs baseline: 1.6147x; 1.6147x over previous
//
#include <hip/hip_runtime.h>

#define NN 100000
#define NE 1600000
#define NG 512
#define FIN 226
#define HD 128
#define BN_EPS 1e-5f

typedef __attribute__((ext_vector_type(8))) __bf16 bf16x8;
typedef __attribute__((ext_vector_type(8))) short short8;
typedef __attribute__((ext_vector_type(8))) unsigned short ushort8;
typedef __attribute__((ext_vector_type(4))) float f32x4;

#define BC(x) __builtin_bit_cast(bf16x8, x)

__device__ inline unsigned short f2bf(float v) {
  unsigned u = __builtin_bit_cast(unsigned, v);
  return (unsigned short)((u + 0x7FFFu + ((u >> 16) & 1u)) >> 16);
}
__device__ inline float bf2f(unsigned short b) {
  return __builtin_bit_cast(float, (unsigned)b << 16);
}

// ---------------- CSR build ----------------
__global__ void k_hist(const int* __restrict__ dst, int* __restrict__ counts) {
  int e = blockIdx.x * 256 + threadIdx.x;
  if (e < NE) atomicAdd(&counts[dst[e]], 1);
}

__global__ __launch_bounds__(1024) void k_scan(const int* __restrict__ counts,
                                               int* __restrict__ row_ptr) {
  __shared__ int wtot[16];
  __shared__ int woff[16];
  __shared__ int carry;
  const int tid = threadIdx.x;
  const int lane = tid & 63, wid = tid >> 6;
  if (tid == 0) { carry = 0; row_ptr[0] = 0; }
  __syncthreads();
  for (int base = 0; base < NN; base += 1024) {
    int i = base + tid;
    int v = (i < NN) ? counts[i] : 0;
    int incl = v;
    #pragma unroll
    for (int off = 1; off < 64; off <<= 1) {
      int u = __shfl_up(incl, off);
      if (lane >= off) incl += u;
    }
    if (lane == 63) wtot[wid] = incl;
    __syncthreads();
    if (tid == 0) {
      int run = carry;
      #pragma unroll
      for (int w = 0; w < 16; ++w) { woff[w] = run; run += wtot[w]; }
      carry = run;
    }
    __syncthreads();
    if (i < NN) row_ptr[i + 1] = woff[wid] + incl;
  }
}

__global__ void k_fill(const int* __restrict__ src, const int* __restrict__ dst,
                       const int* __restrict__ row_ptr, int* __restrict__ cursor,
                       int* __restrict__ col_idx) {
  int e = blockIdx.x * 256 + threadIdx.x;
  if (e < NE) {
    int d = dst[e];
    int pos = row_ptr[d] + atomicAdd(&cursor[d], 1);
    col_idx[pos] = src[e];
  }
}

// ---------------- weight prep: fold BN scale, split hi/lo bf16, transpose, swizzle ----
// Output layout per chunk (128 k-rows): [chunk][hi(16384) | lo(16384)] ushort,
// element index within slab for (col n, k kk): n*128 + (kk ^ ((n&7)<<3))
__global__ void k_prepw(const float* __restrict__ W, const float* __restrict__ g,
                        const float* __restrict__ rv, unsigned short* __restrict__ out,
                        int K, int nchunks) {
  int id = blockIdx.x * 256 + threadIdx.x;
  if (id >= nchunks * 128 * 128) return;
  int kg = id >> 7;          // global k row (padded)
  int n = id & 127;          // output column
  int chunk = kg >> 7, kk = kg & 127;
  float s = g ? g[n] * rsqrtf(rv[n] + BN_EPS) : 1.f;
  float v = (kg < K) ? W[(size_t)kg * HD + n] * s : 0.f;
  unsigned short hb = f2bf(v);
  unsigned short lb = f2bf(v - bf2f(hb));
  int idx = n * 128 + (kk ^ ((n & 7) << 3));
  out[(size_t)chunk * 32768 + idx] = hb;
  out[(size_t)chunk * 32768 + 16384 + idx] = lb;
}

__global__ void k_bias(const float* __restrict__ ba, const float* __restrict__ g,
                       const float* __restrict__ be, const float* __restrict__ rm,
                       const float* __restrict__ rv, float* __restrict__ bout) {
  int c = threadIdx.x;
  if (c < HD) {
    float s = g[c] * rsqrtf(rv[c] + BN_EPS);
    bout[c] = ba[c] * s + be[c] - rm[c] * s;
  }
}

// ---------------- bf16x3 MFMA GEMM: [M x K] fp32 @ [K x 128] -> [M x 128] fp32 ----
// block 256 = 4 waves; BM=128 (wave: 32 rows = 2 Mfrags), N=128 (8 Nfrags), BK=128 chunks
template <int BIAS, int RELU>
__global__ __launch_bounds__(256) void k_mgemm(const float* __restrict__ A,
                                               const unsigned short* __restrict__ Wz,
                                               const float* __restrict__ bias,
                                               float* __restrict__ out,
                                               int K, int nchunks) {
  __shared__ unsigned short sW[32768];  // 64 KiB: hi slab [16384] then lo slab
  const int tid = threadIdx.x;
  const int wv = tid >> 6, ln = tid & 63;
  const int l15 = ln & 15, l4 = ln >> 4;
  const int m0 = blockIdx.x * 128 + wv * 32;
  f32x4 acc[2][8] = {};

  const int sw = (l15 & 7) << 3;
  int kofs[4];
  #pragma unroll
  for (int ks = 0; ks < 4; ++ks) kofs[ks] = (((ks * 32 + l4 * 8) ^ sw)) + l15 * 128;

  for (int c = 0; c < nchunks; ++c) {
    // stage 64KB of pre-swizzled W into LDS (linear copy)
    {
      const ushort8* src = (const ushort8*)(Wz + (size_t)c * 32768);
      ushort8* dst = (ushort8*)sW;
      #pragma unroll
      for (int i = 0; i < 16; ++i) dst[tid + i * 256] = src[tid + i * 256];
    }
    __syncthreads();
    const int kc = c * 128;
    #pragma unroll
    for (int ks = 0; ks < 4; ++ks) {
      const int kbase = kc + ks * 32 + l4 * 8;
      const bool tail = (kc + ks * 32 + 32) > K;  // uniform across block
      short8 ah[2], al[2];
      #pragma unroll
      for (int mf = 0; mf < 2; ++mf) {
        const int row = m0 + mf * 16 + l15;
        float v[8];
        if (row < NN && !tail) {
          const float2* ap = (const float2*)(A + (size_t)row * K + kbase);
          #pragma unroll
          for (int q = 0; q < 4; ++q) { float2 t = ap[q]; v[2*q] = t.x; v[2*q+1] = t.y; }
        } else if (row < NN) {
          #pragma unroll
          for (int j = 0; j < 8; ++j) {
            int k = kbase + j;
            v[j] = (k < K) ? A[(size_t)row * K + k] : 0.f;
          }
        } else {
          #pragma unroll
          for (int j = 0; j < 8; ++j) v[j] = 0.f;
        }
        #pragma unroll
        for (int j = 0; j < 8; ++j) {
          unsigned short hb = f2bf(v[j]);
          ah[mf][j] = (short)hb;
          al[mf][j] = (short)f2bf(v[j] - bf2f(hb));
        }
      }
      #pragma unroll
      for (int n = 0; n < 8; ++n) {
        const int idx = n * 2048 + kofs[ks];
        short8 bh = *(const short8*)&sW[idx];
        short8 bl = *(const short8*)&sW[idx + 16384];
        #pragma unroll
        for (int mf = 0; mf < 2; ++mf) {
          acc[mf][n] = __builtin_amdgcn_mfma_f32_16x16x32_bf16(BC(ah[mf]), BC(bh), acc[mf][n], 0, 0, 0);
          acc[mf][n] = __builtin_amdgcn_mfma_f32_16x16x32_bf16(BC(ah[mf]), BC(bl), acc[mf][n], 0, 0, 0);
          acc[mf][n] = __builtin_amdgcn_mfma_f32_16x16x32_bf16(BC(al[mf]), BC(bh), acc[mf][n], 0, 0, 0);
        }
      }
    }
    __syncthreads();
  }

  // epilogue: C/D layout row=(l>>4)*4+r, col=l&15
  #pragma unroll
  for (int mf = 0; mf < 2; ++mf) {
    #pragma unroll
    for (int n = 0; n < 8; ++n) {
      const int col = n * 16 + l15;
      float bv = 0.f;
      if (BIAS) bv = bias[col];
      #pragma unroll
      for (int r = 0; r < 4; ++r) {
        const int row = m0 + mf * 16 + l4 * 4 + r;
        if (row < NN) {
          float o = acc[mf][n][r] + bv;
          if (RELU) o = fmaxf(o, 0.f);
          out[(size_t)row * HD + col] = o;
        }
      }
    }
  }
}

// ---------------- aggregation: h[i] = relu(y[i] + sum_j y[j] + bias) ----------------
__global__ __launch_bounds__(256) void k_agg(const float* __restrict__ y,
                                             const int* __restrict__ row_ptr,
                                             const int* __restrict__ col_idx,
                                             const float* __restrict__ bias,
                                             float* __restrict__ h) {
  const int node = blockIdx.x * 4 + (threadIdx.x >> 6);
  const int lane = threadIdx.x & 63;
  if (node >= NN) return;
  const float2* y2 = reinterpret_cast<const float2*>(y);
  float2 acc = y2[(size_t)node * 64 + lane];
  const int beg = row_ptr[node], end = row_ptr[node + 1];
  for (int e = beg; e < end; ++e) {
    const int s = col_idx[e];
    const float2 v = y2[(size_t)s * 64 + lane];
    acc.x += v.x; acc.y += v.y;
  }
  const float2 b = reinterpret_cast<const float2*>(bias)[lane];
  float2 o;
  o.x = fmaxf(acc.x + b.x, 0.f);
  o.y = fmaxf(acc.y + b.y, 0.f);
  reinterpret_cast<float2*>(h)[(size_t)node * 64 + lane] = o;
}

// ---------------- pooling: hierarchical (LDS bins -> few global atomics) ----------
__global__ __launch_bounds__(256) void k_pool2(const float* __restrict__ h,
                                               const int* __restrict__ batch,
                                               const float* __restrict__ Wl,
                                               float* __restrict__ sums,
                                               float* __restrict__ cnts) {
  __shared__ float sb[NG];
  __shared__ int sc[NG];
  const int tid = threadIdx.x;
  for (int i = tid; i < NG; i += 256) { sb[i] = 0.f; sc[i] = 0; }
  __syncthreads();
  const int wv = tid >> 6, ln = tid & 63;
  const float2 w2 = reinterpret_cast<const float2*>(Wl)[ln];
  #pragma unroll 1
  for (int i = 0; i < 16; ++i) {
    const int node = blockIdx.x * 64 + wv * 16 + i;
    if (node < NN) {
      const float2 hv = reinterpret_cast<const float2*>(h)[(size_t)node * 64 + ln];
      float d = hv.x * w2.x + hv.y * w2.y;
      #pragma unroll
      for (int off = 32; off > 0; off >>= 1) d += __shfl_down(d, off);
      if (ln == 0) {
        const int g = batch[node];
        atomicAdd(&sb[g], d);
        atomicAdd(&sc[g], 1);
      }
    }
  }
  __syncthreads();
  for (int i = tid; i < NG; i += 256)
    if (sc[i]) { atomicAdd(&sums[i], sb[i]); atomicAdd(&cnts[i], (float)sc[i]); }
}

__global__ void k_final(const float* __restrict__ sums, const float* __restrict__ cnts,
                        const float* __restrict__ bl, float* __restrict__ out) {
  int g = blockIdx.x * 256 + threadIdx.x;
  if (g < NG) out[g] = sums[g] / fmaxf(cnts[g], 1.f) + bl[0];
}

// ---------------- launch ----------------
extern "C" void kernel_launch(void* const* d_in, const int* in_sizes, int n_in,
                              void* d_out, int out_size, void* d_ws, size_t ws_size,
                              hipStream_t stream) {
  const float* x = (const float*)d_in[0];
  const int* edges = (const int*)d_in[1];
  const int* batch = (const int*)d_in[2];
  const int* e_src = edges;
  const int* e_dst = edges + NE;
  const float* Wl = (const float*)d_in[35];
  const float* bl = (const float*)d_in[36];
  float* out = (float*)d_out;
  auto P = [&](int l, int which) -> const float* {
    return (const float*)d_in[3 + (l - 1) * 8 + which];
  };
  // which: 0=Wa 1=ba 2=g 3=be 4=rm 5=rv 6=Wb 7=bb

  char* ws = (char*)d_ws;
  size_t off = 0;
  auto take = [&](size_t bytes) -> void* {
    void* p = ws + off;
    off = (off + bytes + 255) & ~(size_t)255;
    return p;
  };
  float* Y = (float*)take((size_t)NN * HD * 4);
  float* H = (float*)take((size_t)NN * HD * 4);
  float* X = (float*)take((size_t)NN * HD * 4);
  int* row_ptr = (int*)take((size_t)(NN + 1) * 4);
  int* cnt = (int*)take((size_t)NN * 4);
  int* col_idx = (int*)take((size_t)NE * 4);
  // swizzled split weights: Wa1 has 2 chunks, others 1 chunk (32768 ushort each)
  unsigned short* Wza[4];
  unsigned short* Wzb[4];
  Wza[0] = (unsigned short*)take((size_t)2 * 32768 * 2);
  for (int l = 1; l < 4; ++l) Wza[l] = (unsigned short*)take((size_t)32768 * 2);
  for (int l = 0; l < 4; ++l) Wzb[l] = (unsigned short*)take((size_t)32768 * 2);
  float* bf = (float*)take((size_t)4 * HD * 4);
  float* psum = (float*)take((size_t)NG * 4 * 2);
  float* pcnt = psum + NG;

  // CSR build
  hipMemsetAsync(cnt, 0, (size_t)NN * 4, stream);
  k_hist<<<(NE + 255) / 256, 256, 0, stream>>>(e_dst, cnt);
  k_scan<<<1, 1024, 0, stream>>>(cnt, row_ptr);
  hipMemsetAsync(cnt, 0, (size_t)NN * 4, stream);
  k_fill<<<(NE + 255) / 256, 256, 0, stream>>>(e_src, e_dst, row_ptr, cnt, col_idx);

  // weight prep
  k_prepw<<<(2 * 128 * 128 + 255) / 256, 256, 0, stream>>>(P(1, 0), P(1, 2), P(1, 5), Wza[0], FIN, 2);
  for (int l = 2; l <= 4; ++l)
    k_prepw<<<(128 * 128 + 255) / 256, 256, 0, stream>>>(P(l, 0), P(l, 2), P(l, 5), Wza[l - 1], HD, 1);
  for (int l = 1; l <= 4; ++l)
    k_prepw<<<(128 * 128 + 255) / 256, 256, 0, stream>>>(P(l, 6), nullptr, nullptr, Wzb[l - 1], HD, 1);
  for (int l = 1; l <= 4; ++l)
    k_bias<<<1, 128, 0, stream>>>(P(l, 1), P(l, 2), P(l, 3), P(l, 4), P(l, 5), bf + (l - 1) * HD);

  hipMemsetAsync(psum, 0, (size_t)NG * 8, stream);

  const int gemm_grid = (NN + 127) / 128;
  // y1 = x @ W1a'
  k_mgemm<0, 0><<<gemm_grid, 256, 0, stream>>>(x, Wza[0], nullptr, Y, FIN, 2);
  for (int l = 1; l <= 4; ++l) {
    // h = relu(y + agg(y) + ba')
    k_agg<<<NN / 4, 256, 0, stream>>>(Y, row_ptr, col_idx, bf + (l - 1) * HD, H);
    // x_next = relu(h @ Wb + bb)
    k_mgemm<1, 1><<<gemm_grid, 256, 0, stream>>>(H, Wzb[l - 1], P(l, 7), X, HD, 1);
    // y_{l+1} = x_next @ W(l+1)a'
    if (l < 4)
      k_mgemm<0, 0><<<gemm_grid, 256, 0, stream>>>(X, Wza[l], nullptr, Y, HD, 1);
  }
  k_pool2<<<(NN + 63) / 64, 256, 0, stream>>>(X, batch, Wl, psum, pcnt);
  k_final<<<(NG + 255) / 256, 256, 0, stream>>>(psum, pcnt, bl, out);
}

// Round 3
// 886.512 us; speedup vs baseline: 2.1637x; 1.3401x over previous
//
#include <hip/hip_runtime.h>

#define NN 100000
#define NE 1600000
#define NG 512
#define FIN 226
#define HD 128
#define BN_EPS 1e-5f

typedef __attribute__((ext_vector_type(8))) __bf16 bf16x8;
typedef __attribute__((ext_vector_type(8))) short short8;
typedef __attribute__((ext_vector_type(8))) unsigned short ushort8;
typedef __attribute__((ext_vector_type(4))) float f32x4;

#define BC(x) __builtin_bit_cast(bf16x8, x)

__device__ inline unsigned short f2bf(float v) {
  unsigned u = __builtin_bit_cast(unsigned, v);
  return (unsigned short)((u + 0x7FFFu + ((u >> 16) & 1u)) >> 16);
}
__device__ inline float bf2f(unsigned short b) {
  return __builtin_bit_cast(float, (unsigned)b << 16);
}

// ---------------- CSR build ----------------
__global__ void k_hist(const int* __restrict__ dst, int* __restrict__ counts) {
  int e = blockIdx.x * 256 + threadIdx.x;
  if (e < NE) atomicAdd(&counts[dst[e]], 1);
}

__global__ __launch_bounds__(1024) void k_scan(const int* __restrict__ counts,
                                               int* __restrict__ row_ptr) {
  __shared__ int wtot[16];
  __shared__ int woff[16];
  __shared__ int carry;
  const int tid = threadIdx.x;
  const int lane = tid & 63, wid = tid >> 6;
  if (tid == 0) { carry = 0; row_ptr[0] = 0; }
  __syncthreads();
  for (int base = 0; base < NN; base += 1024) {
    int i = base + tid;
    int v = (i < NN) ? counts[i] : 0;
    int incl = v;
    #pragma unroll
    for (int off = 1; off < 64; off <<= 1) {
      int u = __shfl_up(incl, off);
      if (lane >= off) incl += u;
    }
    if (lane == 63) wtot[wid] = incl;
    __syncthreads();
    if (tid == 0) {
      int run = carry;
      #pragma unroll
      for (int w = 0; w < 16; ++w) { woff[w] = run; run += wtot[w]; }
      carry = run;
    }
    __syncthreads();
    if (i < NN) row_ptr[i + 1] = woff[wid] + incl;
  }
}

__global__ void k_fill(const int* __restrict__ src, const int* __restrict__ dst,
                       const int* __restrict__ row_ptr, int* __restrict__ cursor,
                       int* __restrict__ col_idx) {
  int e = blockIdx.x * 256 + threadIdx.x;
  if (e < NE) {
    int d = dst[e];
    int pos = row_ptr[d] + atomicAdd(&cursor[d], 1);
    col_idx[pos] = src[e];
  }
}

// ---------------- weight prep: fold BN scale, split hi/lo bf16, transpose, swizzle ----
// layout per chunk (128 k): [hi 16384 | lo 16384] ushort; elem (col n, kk): n*128 + (kk ^ ((n&7)<<3))
__global__ void k_prepw(const float* __restrict__ W, const float* __restrict__ g,
                        const float* __restrict__ rv, unsigned short* __restrict__ out,
                        int K, int nchunks) {
  int id = blockIdx.x * 256 + threadIdx.x;
  if (id >= nchunks * 128 * 128) return;
  int kg = id >> 7;
  int n = id & 127;
  int chunk = kg >> 7, kk = kg & 127;
  float s = g ? g[n] * rsqrtf(rv[n] + BN_EPS) : 1.f;
  float v = (kg < K) ? W[(size_t)kg * HD + n] * s : 0.f;
  unsigned short hb = f2bf(v);
  unsigned short lb = f2bf(v - bf2f(hb));
  int idx = n * 128 + (kk ^ ((n & 7) << 3));
  out[(size_t)chunk * 32768 + idx] = hb;
  out[(size_t)chunk * 32768 + 16384 + idx] = lb;
}

__global__ void k_bias(const float* __restrict__ ba, const float* __restrict__ g,
                       const float* __restrict__ be, const float* __restrict__ rm,
                       const float* __restrict__ rv, float* __restrict__ bout) {
  int c = threadIdx.x;
  if (c < HD) {
    float s = g[c] * rsqrtf(rv[c] + BN_EPS);
    bout[c] = ba[c] * s + be[c] - rm[c] * s;
  }
}

// ---------------- GEMM1: f32 A (x) bf16x3 split @ [K x 128] -> bf16 out ----------------
__global__ __launch_bounds__(256) void k_mgemm1(const float* __restrict__ A,
                                                const unsigned short* __restrict__ Wz,
                                                unsigned short* __restrict__ out,
                                                int K, int nchunks) {
  __shared__ unsigned short sW[32768];
  const int tid = threadIdx.x;
  const int wv = tid >> 6, ln = tid & 63;
  const int l15 = ln & 15, l4 = ln >> 4;
  const int m0 = blockIdx.x * 128 + wv * 32;
  f32x4 acc[2][8] = {};
  const int sw = (l15 & 7) << 3;
  int kofs[4];
  #pragma unroll
  for (int ks = 0; ks < 4; ++ks) kofs[ks] = (((ks * 32 + l4 * 8) ^ sw)) + l15 * 128;

  for (int c = 0; c < nchunks; ++c) {
    {
      const ushort8* src = (const ushort8*)(Wz + (size_t)c * 32768);
      ushort8* dst = (ushort8*)sW;
      #pragma unroll
      for (int i = 0; i < 16; ++i) dst[tid + i * 256] = src[tid + i * 256];
    }
    __syncthreads();
    const int kc = c * 128;
    #pragma unroll
    for (int ks = 0; ks < 4; ++ks) {
      const int kbase = kc + ks * 32 + l4 * 8;
      const bool tail = (kc + ks * 32 + 32) > K;
      short8 ah[2], al[2];
      #pragma unroll
      for (int mf = 0; mf < 2; ++mf) {
        const int row = m0 + mf * 16 + l15;
        float v[8];
        if (row < NN && !tail) {
          const float2* ap = (const float2*)(A + (size_t)row * K + kbase);
          #pragma unroll
          for (int q = 0; q < 4; ++q) { float2 t = ap[q]; v[2*q] = t.x; v[2*q+1] = t.y; }
        } else if (row < NN) {
          #pragma unroll
          for (int j = 0; j < 8; ++j) {
            int k = kbase + j;
            v[j] = (k < K) ? A[(size_t)row * K + k] : 0.f;
          }
        } else {
          #pragma unroll
          for (int j = 0; j < 8; ++j) v[j] = 0.f;
        }
        #pragma unroll
        for (int j = 0; j < 8; ++j) {
          unsigned short hb = f2bf(v[j]);
          ah[mf][j] = (short)hb;
          al[mf][j] = (short)f2bf(v[j] - bf2f(hb));
        }
      }
      #pragma unroll
      for (int n = 0; n < 8; ++n) {
        const int idx = n * 2048 + kofs[ks];
        short8 bh = *(const short8*)&sW[idx];
        short8 bl = *(const short8*)&sW[idx + 16384];
        #pragma unroll
        for (int mf = 0; mf < 2; ++mf) {
          acc[mf][n] = __builtin_amdgcn_mfma_f32_16x16x32_bf16(BC(ah[mf]), BC(bh), acc[mf][n], 0, 0, 0);
          acc[mf][n] = __builtin_amdgcn_mfma_f32_16x16x32_bf16(BC(ah[mf]), BC(bl), acc[mf][n], 0, 0, 0);
          acc[mf][n] = __builtin_amdgcn_mfma_f32_16x16x32_bf16(BC(al[mf]), BC(bh), acc[mf][n], 0, 0, 0);
        }
      }
    }
    __syncthreads();
  }
  #pragma unroll
  for (int mf = 0; mf < 2; ++mf) {
    #pragma unroll
    for (int n = 0; n < 8; ++n) {
      const int col = n * 16 + l15;
      #pragma unroll
      for (int r = 0; r < 4; ++r) {
        const int row = m0 + mf * 16 + l4 * 4 + r;
        if (row < NN) out[(size_t)row * HD + col] = f2bf(acc[mf][n][r]);
      }
    }
  }
}

// ---------------- GEMM (layers >=2): bf16 A @ (Wh+Wl) -> bf16 out, K=128 ----------------
template <int BIAS, int RELU>
__global__ __launch_bounds__(256) void k_mgemmB(const unsigned short* __restrict__ A,
                                                const unsigned short* __restrict__ Wz,
                                                const float* __restrict__ bias,
                                                unsigned short* __restrict__ out) {
  __shared__ unsigned short sW[32768];
  const int tid = threadIdx.x;
  const int wv = tid >> 6, ln = tid & 63;
  const int l15 = ln & 15, l4 = ln >> 4;
  const int m0 = blockIdx.x * 128 + wv * 32;
  f32x4 acc[2][8] = {};
  const int sw = (l15 & 7) << 3;
  {
    const ushort8* src = (const ushort8*)Wz;
    ushort8* dst = (ushort8*)sW;
    #pragma unroll
    for (int i = 0; i < 16; ++i) dst[tid + i * 256] = src[tid + i * 256];
  }
  __syncthreads();
  #pragma unroll
  for (int ks = 0; ks < 4; ++ks) {
    const int kbase = ks * 32 + l4 * 8;
    short8 a[2];
    #pragma unroll
    for (int mf = 0; mf < 2; ++mf) {
      const int row = m0 + mf * 16 + l15;
      if (row < NN) a[mf] = *(const short8*)(A + (size_t)row * HD + kbase);
      else a[mf] = short8{0, 0, 0, 0, 0, 0, 0, 0};
    }
    const int kof = (kbase ^ sw) + l15 * 128;
    #pragma unroll
    for (int n = 0; n < 8; ++n) {
      const int idx = n * 2048 + kof;
      short8 bh = *(const short8*)&sW[idx];
      short8 bl = *(const short8*)&sW[idx + 16384];
      #pragma unroll
      for (int mf = 0; mf < 2; ++mf) {
        acc[mf][n] = __builtin_amdgcn_mfma_f32_16x16x32_bf16(BC(a[mf]), BC(bh), acc[mf][n], 0, 0, 0);
        acc[mf][n] = __builtin_amdgcn_mfma_f32_16x16x32_bf16(BC(a[mf]), BC(bl), acc[mf][n], 0, 0, 0);
      }
    }
  }
  #pragma unroll
  for (int mf = 0; mf < 2; ++mf) {
    #pragma unroll
    for (int n = 0; n < 8; ++n) {
      const int col = n * 16 + l15;
      float bv = BIAS ? bias[col] : 0.f;
      #pragma unroll
      for (int r = 0; r < 4; ++r) {
        const int row = m0 + mf * 16 + l4 * 4 + r;
        if (row < NN) {
          float o = acc[mf][n][r] + bv;
          if (RELU) o = fmaxf(o, 0.f);
          out[(size_t)row * HD + col] = f2bf(o);
        }
      }
    }
  }
}

// ---------------- aggregation (bf16): h = relu(y_self + sum y_nb + bias) ----------------
__global__ __launch_bounds__(256) void k_agg(const unsigned short* __restrict__ y,
                                             const int* __restrict__ row_ptr,
                                             const int* __restrict__ col_idx,
                                             const float* __restrict__ bias,
                                             unsigned short* __restrict__ h) {
  const int node = blockIdx.x * 4 + (threadIdx.x >> 6);
  const int lane = threadIdx.x & 63;
  if (node >= NN) return;
  const ushort2* y2 = reinterpret_cast<const ushort2*>(y);
  ushort2 s = y2[(size_t)node * 64 + lane];
  float ax = bf2f(s.x), ay = bf2f(s.y);
  float bx = 0.f, by = 0.f;
  const int beg = row_ptr[node], end = row_ptr[node + 1];
  int e = beg;
  for (; e + 2 <= end; e += 2) {
    const int s0 = col_idx[e], s1 = col_idx[e + 1];
    const ushort2 v0 = y2[(size_t)s0 * 64 + lane];
    const ushort2 v1 = y2[(size_t)s1 * 64 + lane];
    ax += bf2f(v0.x); ay += bf2f(v0.y);
    bx += bf2f(v1.x); by += bf2f(v1.y);
  }
  if (e < end) {
    const ushort2 v0 = y2[(size_t)col_idx[e] * 64 + lane];
    ax += bf2f(v0.x); ay += bf2f(v0.y);
  }
  const float2 b = reinterpret_cast<const float2*>(bias)[lane];
  ushort2 o;
  o.x = f2bf(fmaxf(ax + bx + b.x, 0.f));
  o.y = f2bf(fmaxf(ay + by + b.y, 0.f));
  reinterpret_cast<ushort2*>(h)[(size_t)node * 64 + lane] = o;
}

// ---------------- pooling: hierarchical (LDS bins -> few global atomics) ----------
__global__ __launch_bounds__(256) void k_pool2(const unsigned short* __restrict__ h,
                                               const int* __restrict__ batch,
                                               const float* __restrict__ Wl,
                                               float* __restrict__ sums,
                                               float* __restrict__ cnts) {
  __shared__ float sb[NG];
  __shared__ int sc[NG];
  const int tid = threadIdx.x;
  for (int i = tid; i < NG; i += 256) { sb[i] = 0.f; sc[i] = 0; }
  __syncthreads();
  const int wv = tid >> 6, ln = tid & 63;
  const float2 w2 = reinterpret_cast<const float2*>(Wl)[ln];
  #pragma unroll 1
  for (int i = 0; i < 16; ++i) {
    const int node = blockIdx.x * 64 + wv * 16 + i;
    if (node < NN) {
      const ushort2 hv = reinterpret_cast<const ushort2*>(h)[(size_t)node * 64 + ln];
      float d = bf2f(hv.x) * w2.x + bf2f(hv.y) * w2.y;
      #pragma unroll
      for (int off = 32; off > 0; off >>= 1) d += __shfl_down(d, off);
      if (ln == 0) {
        const int g = batch[node];
        atomicAdd(&sb[g], d);
        atomicAdd(&sc[g], 1);
      }
    }
  }
  __syncthreads();
  for (int i = tid; i < NG; i += 256)
    if (sc[i]) { atomicAdd(&sums[i], sb[i]); atomicAdd(&cnts[i], (float)sc[i]); }
}

__global__ void k_final(const float* __restrict__ sums, const float* __restrict__ cnts,
                        const float* __restrict__ bl, float* __restrict__ out) {
  int g = blockIdx.x * 256 + threadIdx.x;
  if (g < NG) out[g] = sums[g] / fmaxf(cnts[g], 1.f) + bl[0];
}

// ---------------- launch ----------------
extern "C" void kernel_launch(void* const* d_in, const int* in_sizes, int n_in,
                              void* d_out, int out_size, void* d_ws, size_t ws_size,
                              hipStream_t stream) {
  const float* x = (const float*)d_in[0];
  const int* edges = (const int*)d_in[1];
  const int* batch = (const int*)d_in[2];
  const int* e_src = edges;
  const int* e_dst = edges + NE;
  const float* Wl = (const float*)d_in[35];
  const float* bl = (const float*)d_in[36];
  float* out = (float*)d_out;
  auto P = [&](int l, int which) -> const float* {
    return (const float*)d_in[3 + (l - 1) * 8 + which];
  };
  // which: 0=Wa 1=ba 2=g 3=be 4=rm 5=rv 6=Wb 7=bb

  char* ws = (char*)d_ws;
  size_t off = 0;
  auto take = [&](size_t bytes) -> void* {
    void* p = ws + off;
    off = (off + bytes + 255) & ~(size_t)255;
    return p;
  };
  unsigned short* Y = (unsigned short*)take((size_t)NN * HD * 2);
  unsigned short* H = (unsigned short*)take((size_t)NN * HD * 2);
  unsigned short* X = (unsigned short*)take((size_t)NN * HD * 2);
  int* row_ptr = (int*)take((size_t)(NN + 1) * 4);
  int* cnt = (int*)take((size_t)NN * 4);
  int* col_idx = (int*)take((size_t)NE * 4);
  unsigned short* Wza[4];
  unsigned short* Wzb[4];
  Wza[0] = (unsigned short*)take((size_t)2 * 32768 * 2);
  for (int l = 1; l < 4; ++l) Wza[l] = (unsigned short*)take((size_t)32768 * 2);
  for (int l = 0; l < 4; ++l) Wzb[l] = (unsigned short*)take((size_t)32768 * 2);
  float* bf = (float*)take((size_t)4 * HD * 4);
  float* psum = (float*)take((size_t)NG * 4 * 2);
  float* pcnt = psum + NG;

  // CSR build
  hipMemsetAsync(cnt, 0, (size_t)NN * 4, stream);
  k_hist<<<(NE + 255) / 256, 256, 0, stream>>>(e_dst, cnt);
  k_scan<<<1, 1024, 0, stream>>>(cnt, row_ptr);
  hipMemsetAsync(cnt, 0, (size_t)NN * 4, stream);
  k_fill<<<(NE + 255) / 256, 256, 0, stream>>>(e_src, e_dst, row_ptr, cnt, col_idx);

  // weight prep
  k_prepw<<<(2 * 128 * 128 + 255) / 256, 256, 0, stream>>>(P(1, 0), P(1, 2), P(1, 5), Wza[0], FIN, 2);
  for (int l = 2; l <= 4; ++l)
    k_prepw<<<(128 * 128 + 255) / 256, 256, 0, stream>>>(P(l, 0), P(l, 2), P(l, 5), Wza[l - 1], HD, 1);
  for (int l = 1; l <= 4; ++l)
    k_prepw<<<(128 * 128 + 255) / 256, 256, 0, stream>>>(P(l, 6), nullptr, nullptr, Wzb[l - 1], HD, 1);
  for (int l = 1; l <= 4; ++l)
    k_bias<<<1, 128, 0, stream>>>(P(l, 1), P(l, 2), P(l, 3), P(l, 4), P(l, 5), bf + (l - 1) * HD);

  hipMemsetAsync(psum, 0, (size_t)NG * 8, stream);

  const int gemm_grid = (NN + 127) / 128;
  // y1 = x @ W1a'  (f32 A path, K=226)
  k_mgemm1<<<gemm_grid, 256, 0, stream>>>(x, Wza[0], Y, FIN, 2);
  for (int l = 1; l <= 4; ++l) {
    // h = relu(y + agg(y) + ba')
    k_agg<<<NN / 4, 256, 0, stream>>>(Y, row_ptr, col_idx, bf + (l - 1) * HD, H);
    // x_next = relu(h @ Wb + bb)
    k_mgemmB<1, 1><<<gemm_grid, 256, 0, stream>>>(H, Wzb[l - 1], P(l, 7), X);
    // y_{l+1} = x_next @ W(l+1)a'
    if (l < 4)
      k_mgemmB<0, 0><<<gemm_grid, 256, 0, stream>>>(X, Wza[l], nullptr, Y);
  }
  k_pool2<<<(NN + 63) / 64, 256, 0, stream>>>(X, batch, Wl, psum, pcnt);
  k_final<<<(NG + 255) / 256, 256, 0, stream>>>(psum, pcnt, bl, out);
}

// Round 4
// 703.561 us; speedup vs baseline: 2.7264x; 1.2600x over previous
//
#include <hip/hip_runtime.h>

#define NN 100000
#define NE 1600000
#define NG 512
#define FIN 226
#define HD 128
#define BN_EPS 1e-5f
#define SCAN_B 391  // ceil(NN/256)

typedef __attribute__((ext_vector_type(8))) __bf16 bf16x8;
typedef __attribute__((ext_vector_type(8))) short short8;
typedef __attribute__((ext_vector_type(8))) unsigned short ushort8;
typedef __attribute__((ext_vector_type(4))) float f32x4;
typedef __attribute__((ext_vector_type(2))) float f32x2;
typedef __attribute__((ext_vector_type(2))) int i32x2;
typedef __attribute__((ext_vector_type(4))) int i32x4;

#define BC(x) __builtin_bit_cast(bf16x8, x)

__device__ inline unsigned short f2bf(float v) {
  unsigned u = __builtin_bit_cast(unsigned, v);
  return (unsigned short)((u + 0x7FFFu + ((u >> 16) & 1u)) >> 16);
}
__device__ inline float bf2f(unsigned short b) {
  return __builtin_bit_cast(float, (unsigned)b << 16);
}

// ---------------- CSR build ----------------
__global__ __launch_bounds__(256) void k_hist(const int* __restrict__ dst,
                                              int* __restrict__ counts) {
  int base = (blockIdx.x * 256 + threadIdx.x) * 4;
  if (base + 4 <= NE) {
    i32x4 d = __builtin_nontemporal_load((const i32x4*)(dst + base));
    atomicAdd(&counts[d[0]], 1);
    atomicAdd(&counts[d[1]], 1);
    atomicAdd(&counts[d[2]], 1);
    atomicAdd(&counts[d[3]], 1);
  }
}

__global__ __launch_bounds__(256) void k_scan1(const int* __restrict__ c,
                                               int* __restrict__ bsum) {
  __shared__ int ws[4];
  int i = blockIdx.x * 256 + threadIdx.x;
  int t = (i < NN) ? c[i] : 0;
  #pragma unroll
  for (int o = 32; o > 0; o >>= 1) t += __shfl_down(t, o);
  if ((threadIdx.x & 63) == 0) ws[threadIdx.x >> 6] = t;
  __syncthreads();
  if (threadIdx.x == 0) bsum[blockIdx.x] = ws[0] + ws[1] + ws[2] + ws[3];
}

__global__ __launch_bounds__(512) void k_scan2(int* __restrict__ bsum) {
  __shared__ int ws[8];
  int i = threadIdx.x;
  int v = (i < SCAN_B) ? bsum[i] : 0;
  int lane = i & 63, w = i >> 6;
  int incl = v;
  #pragma unroll
  for (int o = 1; o < 64; o <<= 1) {
    int u = __shfl_up(incl, o);
    if (lane >= o) incl += u;
  }
  if (lane == 63) ws[w] = incl;
  __syncthreads();
  int wo = 0;
  for (int k = 0; k < w; ++k) wo += ws[k];
  if (i < SCAN_B) bsum[i] = wo + incl - v;  // exclusive
}

__global__ __launch_bounds__(256) void k_scan3(const int* __restrict__ c,
                                               const int* __restrict__ bsum,
                                               int* __restrict__ row_ptr,
                                               int* __restrict__ cursor) {
  __shared__ int ws[4];
  int i = blockIdx.x * 256 + threadIdx.x;
  int v = (i < NN) ? c[i] : 0;
  int lane = threadIdx.x & 63, w = threadIdx.x >> 6;
  int incl = v;
  #pragma unroll
  for (int o = 1; o < 64; o <<= 1) {
    int u = __shfl_up(incl, o);
    if (lane >= o) incl += u;
  }
  if (lane == 63) ws[w] = incl;
  __syncthreads();
  int off = bsum[blockIdx.x];
  for (int k = 0; k < w; ++k) off += ws[k];
  if (i < NN) {
    row_ptr[i + 1] = off + incl;
    cursor[i] = off + incl - v;
  }
  if (i == 0) row_ptr[0] = 0;
}

__global__ __launch_bounds__(256) void k_fill(const int* __restrict__ src,
                                              const int* __restrict__ dst,
                                              int* __restrict__ cursor,
                                              int* __restrict__ col_idx) {
  int base = (blockIdx.x * 256 + threadIdx.x) * 2;
  if (base + 2 <= NE) {
    i32x2 d = __builtin_nontemporal_load((const i32x2*)(dst + base));
    i32x2 s = __builtin_nontemporal_load((const i32x2*)(src + base));
    int p0 = atomicAdd(&cursor[d[0]], 1);
    col_idx[p0] = s[0];
    int p1 = atomicAdd(&cursor[d[1]], 1);
    col_idx[p1] = s[1];
  }
}

// ---------------- merged weight/bias prep ----------------
// 9 chunks of 128k x 128n each: [hi 16384 | lo 16384] ushort,
// elem (col n, kk): n*128 + (kk ^ ((n&7)<<3))
struct PrepArgs {
  const float* W[9];
  const float* g[9];
  const float* rv[9];
  unsigned short* out[9];
  int k0[9];
  int K[9];
  const float* ba[4];
  const float* gg[4];
  const float* be[4];
  const float* rm[4];
  const float* rvv[4];
  float* bout;
};

__global__ __launch_bounds__(256) void k_prep(PrepArgs a) {
  int id = blockIdx.x * 256 + threadIdx.x;
  if (id < 9 * 16384) {
    int chunk = id >> 14;
    int r = id & 16383;
    int kk = r >> 7;
    int n = r & 127;
    float s = a.g[chunk] ? a.g[chunk][n] * rsqrtf(a.rv[chunk][n] + BN_EPS) : 1.f;
    int kg = a.k0[chunk] + kk;
    float v = (kg < a.K[chunk]) ? a.W[chunk][(size_t)kg * HD + n] * s : 0.f;
    unsigned short hb = f2bf(v);
    unsigned short lb = f2bf(v - bf2f(hb));
    int idx = n * 128 + (kk ^ ((n & 7) << 3));
    a.out[chunk][idx] = hb;
    a.out[chunk][16384 + idx] = lb;
  } else {
    int t = id - 9 * 16384;
    if (t < 512) {
      int l = t >> 7, c = t & 127;
      float s = a.gg[l][c] * rsqrtf(a.rvv[l][c] + BN_EPS);
      a.bout[l * 128 + c] = a.ba[l][c] * s + a.be[l][c] - a.rm[l][c] * s;
    }
  }
}

// ---------------- GEMM1: f32 A (x) bf16x3 split @ [K x 128] -> bf16 out ----------------
__global__ __launch_bounds__(256) void k_mgemm1(const float* __restrict__ A,
                                                const unsigned short* __restrict__ Wz,
                                                unsigned short* __restrict__ out,
                                                int K, int nchunks) {
  __shared__ unsigned short sW[32768];
  const int tid = threadIdx.x;
  const int wv = tid >> 6, ln = tid & 63;
  const int l15 = ln & 15, l4 = ln >> 4;
  const int m0 = blockIdx.x * 128 + wv * 32;
  f32x4 acc[2][8] = {};
  const int sw = (l15 & 7) << 3;
  int kofs[4];
  #pragma unroll
  for (int ks = 0; ks < 4; ++ks) kofs[ks] = (((ks * 32 + l4 * 8) ^ sw)) + l15 * 128;

  for (int c = 0; c < nchunks; ++c) {
    {
      const ushort8* src = (const ushort8*)(Wz + (size_t)c * 32768);
      ushort8* dst = (ushort8*)sW;
      #pragma unroll
      for (int i = 0; i < 16; ++i) dst[tid + i * 256] = src[tid + i * 256];
    }
    __syncthreads();
    const int kc = c * 128;
    #pragma unroll
    for (int ks = 0; ks < 4; ++ks) {
      const int kbase = kc + ks * 32 + l4 * 8;
      const bool tail = (kc + ks * 32 + 32) > K;
      short8 ah[2], al[2];
      #pragma unroll
      for (int mf = 0; mf < 2; ++mf) {
        const int row = m0 + mf * 16 + l15;
        float v[8];
        if (row < NN && !tail) {
          const f32x2* ap = (const f32x2*)(A + (size_t)row * K + kbase);
          #pragma unroll
          for (int q = 0; q < 4; ++q) {
            f32x2 t = __builtin_nontemporal_load(ap + q);
            v[2 * q] = t[0]; v[2 * q + 1] = t[1];
          }
        } else if (row < NN) {
          #pragma unroll
          for (int j = 0; j < 8; ++j) {
            int k = kbase + j;
            v[j] = (k < K) ? A[(size_t)row * K + k] : 0.f;
          }
        } else {
          #pragma unroll
          for (int j = 0; j < 8; ++j) v[j] = 0.f;
        }
        #pragma unroll
        for (int j = 0; j < 8; ++j) {
          unsigned short hb = f2bf(v[j]);
          ah[mf][j] = (short)hb;
          al[mf][j] = (short)f2bf(v[j] - bf2f(hb));
        }
      }
      #pragma unroll
      for (int n = 0; n < 8; ++n) {
        const int idx = n * 2048 + kofs[ks];
        short8 bh = *(const short8*)&sW[idx];
        short8 bl = *(const short8*)&sW[idx + 16384];
        #pragma unroll
        for (int mf = 0; mf < 2; ++mf) {
          acc[mf][n] = __builtin_amdgcn_mfma_f32_16x16x32_bf16(BC(ah[mf]), BC(bh), acc[mf][n], 0, 0, 0);
          acc[mf][n] = __builtin_amdgcn_mfma_f32_16x16x32_bf16(BC(ah[mf]), BC(bl), acc[mf][n], 0, 0, 0);
          acc[mf][n] = __builtin_amdgcn_mfma_f32_16x16x32_bf16(BC(al[mf]), BC(bh), acc[mf][n], 0, 0, 0);
        }
      }
    }
    __syncthreads();
  }
  #pragma unroll
  for (int mf = 0; mf < 2; ++mf) {
    #pragma unroll
    for (int n = 0; n < 8; ++n) {
      const int col = n * 16 + l15;
      #pragma unroll
      for (int r = 0; r < 4; ++r) {
        const int row = m0 + mf * 16 + l4 * 4 + r;
        if (row < NN) out[(size_t)row * HD + col] = f2bf(acc[mf][n][r]);
      }
    }
  }
}

// ---------------- GEMM (layers >=2): bf16 A @ (Wh+Wl) -> bf16 out, K=128 ----------------
template <int BIAS, int RELU>
__global__ __launch_bounds__(256) void k_mgemmB(const unsigned short* __restrict__ A,
                                                const unsigned short* __restrict__ Wz,
                                                const float* __restrict__ bias,
                                                unsigned short* __restrict__ out) {
  __shared__ unsigned short sW[32768];
  const int tid = threadIdx.x;
  const int wv = tid >> 6, ln = tid & 63;
  const int l15 = ln & 15, l4 = ln >> 4;
  const int m0 = blockIdx.x * 128 + wv * 32;
  f32x4 acc[2][8] = {};
  const int sw = (l15 & 7) << 3;
  {
    const ushort8* src = (const ushort8*)Wz;
    ushort8* dst = (ushort8*)sW;
    #pragma unroll
    for (int i = 0; i < 16; ++i) dst[tid + i * 256] = src[tid + i * 256];
  }
  __syncthreads();
  #pragma unroll
  for (int ks = 0; ks < 4; ++ks) {
    const int kbase = ks * 32 + l4 * 8;
    short8 a[2];
    #pragma unroll
    for (int mf = 0; mf < 2; ++mf) {
      const int row = m0 + mf * 16 + l15;
      if (row < NN) a[mf] = *(const short8*)(A + (size_t)row * HD + kbase);
      else a[mf] = short8{0, 0, 0, 0, 0, 0, 0, 0};
    }
    const int kof = (kbase ^ sw) + l15 * 128;
    #pragma unroll
    for (int n = 0; n < 8; ++n) {
      const int idx = n * 2048 + kof;
      short8 bh = *(const short8*)&sW[idx];
      short8 bl = *(const short8*)&sW[idx + 16384];
      #pragma unroll
      for (int mf = 0; mf < 2; ++mf) {
        acc[mf][n] = __builtin_amdgcn_mfma_f32_16x16x32_bf16(BC(a[mf]), BC(bh), acc[mf][n], 0, 0, 0);
        acc[mf][n] = __builtin_amdgcn_mfma_f32_16x16x32_bf16(BC(a[mf]), BC(bl), acc[mf][n], 0, 0, 0);
      }
    }
  }
  #pragma unroll
  for (int mf = 0; mf < 2; ++mf) {
    #pragma unroll
    for (int n = 0; n < 8; ++n) {
      const int col = n * 16 + l15;
      float bv = BIAS ? bias[col] : 0.f;
      #pragma unroll
      for (int r = 0; r < 4; ++r) {
        const int row = m0 + mf * 16 + l4 * 4 + r;
        if (row < NN) {
          float o = acc[mf][n][r] + bv;
          if (RELU) o = fmaxf(o, 0.f);
          out[(size_t)row * HD + col] = f2bf(o);
        }
      }
    }
  }
}

// ---------------- aggregation (bf16): 16 lanes/row, 4 rows/wave, x2 unroll ----------
__global__ __launch_bounds__(256) void k_agg(const unsigned short* __restrict__ y,
                                             const int* __restrict__ row_ptr,
                                             const int* __restrict__ col_idx,
                                             const float* __restrict__ bias,
                                             unsigned short* __restrict__ h) {
  const int node = blockIdx.x * 4 + (threadIdx.x >> 6);
  const int ln = threadIdx.x & 63;
  const int l15 = ln & 15, grp = ln >> 4;
  if (node >= NN) return;
  float acc[8] = {};
  const int beg = row_ptr[node], end = row_ptr[node + 1];
  int e = beg;
  for (; e + 8 <= end; e += 8) {
    const int s0 = __builtin_nontemporal_load(col_idx + e + grp);
    const int s1 = __builtin_nontemporal_load(col_idx + e + 4 + grp);
    const ushort8 v0 = *(const ushort8*)(y + (size_t)s0 * HD + l15 * 8);
    const ushort8 v1 = *(const ushort8*)(y + (size_t)s1 * HD + l15 * 8);
    #pragma unroll
    for (int j = 0; j < 8; ++j)
      acc[j] += bf2f((unsigned short)v0[j]) + bf2f((unsigned short)v1[j]);
  }
  if (e + 4 <= end) {
    const int s0 = __builtin_nontemporal_load(col_idx + e + grp);
    const ushort8 v0 = *(const ushort8*)(y + (size_t)s0 * HD + l15 * 8);
    #pragma unroll
    for (int j = 0; j < 8; ++j) acc[j] += bf2f((unsigned short)v0[j]);
    e += 4;
  }
  if (e + grp < end) {
    const int s0 = col_idx[e + grp];
    const ushort8 v0 = *(const ushort8*)(y + (size_t)s0 * HD + l15 * 8);
    #pragma unroll
    for (int j = 0; j < 8; ++j) acc[j] += bf2f((unsigned short)v0[j]);
  }
  #pragma unroll
  for (int j = 0; j < 8; ++j) {
    acc[j] += __shfl_xor(acc[j], 16);
    acc[j] += __shfl_xor(acc[j], 32);
  }
  const ushort8 sv = *(const ushort8*)(y + (size_t)node * HD + l15 * 8);
  const f32x4* b4 = (const f32x4*)(bias + l15 * 8);
  const f32x4 b0 = b4[0], b1 = b4[1];
  ushort8 o;
  #pragma unroll
  for (int j = 0; j < 8; ++j) {
    const float bj = (j < 4) ? b0[j] : b1[j - 4];
    o[j] = (unsigned short)f2bf(fmaxf(acc[j] + bf2f((unsigned short)sv[j]) + bj, 0.f));
  }
  if (grp == 0) *(ushort8*)(h + (size_t)node * HD + l15 * 8) = o;
}

// ---------------- pooling ----------------
__global__ __launch_bounds__(256) void k_pool2(const unsigned short* __restrict__ h,
                                               const int* __restrict__ batch,
                                               const float* __restrict__ Wl,
                                               float* __restrict__ sums,
                                               float* __restrict__ cnts) {
  __shared__ float sb[NG];
  __shared__ int sc[NG];
  const int tid = threadIdx.x;
  for (int i = tid; i < NG; i += 256) { sb[i] = 0.f; sc[i] = 0; }
  __syncthreads();
  const int wv = tid >> 6, ln = tid & 63;
  const float2 w2 = reinterpret_cast<const float2*>(Wl)[ln];
  #pragma unroll 1
  for (int i = 0; i < 16; ++i) {
    const int node = blockIdx.x * 64 + wv * 16 + i;
    if (node < NN) {
      const ushort2 hv = reinterpret_cast<const ushort2*>(h)[(size_t)node * 64 + ln];
      float d = bf2f(hv.x) * w2.x + bf2f(hv.y) * w2.y;
      #pragma unroll
      for (int off = 32; off > 0; off >>= 1) d += __shfl_down(d, off);
      if (ln == 0) {
        const int g = batch[node];
        atomicAdd(&sb[g], d);
        atomicAdd(&sc[g], 1);
      }
    }
  }
  __syncthreads();
  for (int i = tid; i < NG; i += 256)
    if (sc[i]) { atomicAdd(&sums[i], sb[i]); atomicAdd(&cnts[i], (float)sc[i]); }
}

__global__ void k_final(const float* __restrict__ sums, const float* __restrict__ cnts,
                        const float* __restrict__ bl, float* __restrict__ out) {
  int g = blockIdx.x * 256 + threadIdx.x;
  if (g < NG) out[g] = sums[g] / fmaxf(cnts[g], 1.f) + bl[0];
}

// ---------------- launch ----------------
extern "C" void kernel_launch(void* const* d_in, const int* in_sizes, int n_in,
                              void* d_out, int out_size, void* d_ws, size_t ws_size,
                              hipStream_t stream) {
  const float* x = (const float*)d_in[0];
  const int* edges = (const int*)d_in[1];
  const int* batch = (const int*)d_in[2];
  const int* e_src = edges;
  const int* e_dst = edges + NE;
  const float* Wl = (const float*)d_in[35];
  const float* bl = (const float*)d_in[36];
  float* out = (float*)d_out;
  auto P = [&](int l, int which) -> const float* {
    return (const float*)d_in[3 + (l - 1) * 8 + which];
  };
  // which: 0=Wa 1=ba 2=g 3=be 4=rm 5=rv 6=Wb 7=bb

  char* ws = (char*)d_ws;
  size_t off = 0;
  auto take = [&](size_t bytes) -> void* {
    void* p = ws + off;
    off = (off + bytes + 255) & ~(size_t)255;
    return p;
  };
  unsigned short* Y = (unsigned short*)take((size_t)NN * HD * 2);
  unsigned short* H = (unsigned short*)take((size_t)NN * HD * 2);
  unsigned short* X = (unsigned short*)take((size_t)NN * HD * 2);
  int* row_ptr = (int*)take((size_t)(NN + 1) * 4);
  int* cnt = (int*)take((size_t)NN * 4);
  int* cursor = (int*)take((size_t)NN * 4);
  int* bsum = (int*)take((size_t)512 * 4);
  int* col_idx = (int*)take((size_t)NE * 4);
  unsigned short* Wza[4];
  unsigned short* Wzb[4];
  Wza[0] = (unsigned short*)take((size_t)2 * 32768 * 2);
  for (int l = 1; l < 4; ++l) Wza[l] = (unsigned short*)take((size_t)32768 * 2);
  for (int l = 0; l < 4; ++l) Wzb[l] = (unsigned short*)take((size_t)32768 * 2);
  float* bf = (float*)take((size_t)4 * HD * 4);
  float* psum = (float*)take((size_t)NG * 4 * 2);
  float* pcnt = psum + NG;

  // CSR build
  hipMemsetAsync(cnt, 0, (size_t)NN * 4, stream);
  k_hist<<<(NE / 4 + 255) / 256, 256, 0, stream>>>(e_dst, cnt);
  k_scan1<<<SCAN_B, 256, 0, stream>>>(cnt, bsum);
  k_scan2<<<1, 512, 0, stream>>>(bsum);
  k_scan3<<<SCAN_B, 256, 0, stream>>>(cnt, bsum, row_ptr, cursor);
  k_fill<<<NE / 2 / 256, 256, 0, stream>>>(e_src, e_dst, cursor, col_idx);

  // merged weight/bias prep
  PrepArgs pa;
  for (int c = 0; c < 9; ++c) {
    if (c < 2) { pa.W[c] = P(1, 0); pa.g[c] = P(1, 2); pa.rv[c] = P(1, 5);
                 pa.out[c] = Wza[0] + c * 32768; pa.k0[c] = c * 128; pa.K[c] = FIN; }
    else if (c < 5) { int l = c - 1; pa.W[c] = P(l + 1, 0); pa.g[c] = P(l + 1, 2);
                      pa.rv[c] = P(l + 1, 5); pa.out[c] = Wza[l]; pa.k0[c] = 0; pa.K[c] = HD; }
    else { int l = c - 5; pa.W[c] = P(l + 1, 6); pa.g[c] = nullptr; pa.rv[c] = nullptr;
           pa.out[c] = Wzb[l]; pa.k0[c] = 0; pa.K[c] = HD; }
  }
  for (int l = 0; l < 4; ++l) {
    pa.ba[l] = P(l + 1, 1); pa.gg[l] = P(l + 1, 2); pa.be[l] = P(l + 1, 3);
    pa.rm[l] = P(l + 1, 4); pa.rvv[l] = P(l + 1, 5);
  }
  pa.bout = bf;
  k_prep<<<(9 * 16384 + 512 + 255) / 256, 256, 0, stream>>>(pa);

  hipMemsetAsync(psum, 0, (size_t)NG * 8, stream);

  const int gemm_grid = (NN + 127) / 128;
  k_mgemm1<<<gemm_grid, 256, 0, stream>>>(x, Wza[0], Y, FIN, 2);
  for (int l = 1; l <= 4; ++l) {
    k_agg<<<NN / 4, 256, 0, stream>>>(Y, row_ptr, col_idx, bf + (l - 1) * HD, H);
    k_mgemmB<1, 1><<<gemm_grid, 256, 0, stream>>>(H, Wzb[l - 1], P(l, 7), X);
    if (l < 4)
      k_mgemmB<0, 0><<<gemm_grid, 256, 0, stream>>>(X, Wza[l], nullptr, Y);
  }
  k_pool2<<<(NN + 63) / 64, 256, 0, stream>>>(X, batch, Wl, psum, pcnt);
  k_final<<<(NG + 255) / 256, 256, 0, stream>>>(psum, pcnt, bl, out);
}

// Round 5
// 533.276 us; speedup vs baseline: 3.5970x; 1.3193x over previous
//
#include <hip/hip_runtime.h>

#define NN 100000
#define NE 1600000
#define NG 512
#define FIN 226
#define HD 128
#define BN_EPS 1e-5f
#define NBUK 196        // ceil(NN/512)
#define BCAP 10016      // per-bucket pair capacity (mean 8163, sigma ~90)

typedef __attribute__((ext_vector_type(8))) __bf16 bf16x8;
typedef __attribute__((ext_vector_type(8))) short short8;
typedef __attribute__((ext_vector_type(8))) unsigned short ushort8;
typedef __attribute__((ext_vector_type(4))) float f32x4;
typedef __attribute__((ext_vector_type(2))) float f32x2;

#define BC(x) __builtin_bit_cast(bf16x8, x)

__device__ inline unsigned short f2bf(float v) {
  unsigned u = __builtin_bit_cast(unsigned, v);
  return (unsigned short)((u + 0x7FFFu + ((u >> 16) & 1u)) >> 16);
}
__device__ inline float bf2f(unsigned short b) {
  return __builtin_bit_cast(float, (unsigned)b << 16);
}

// ---------------- CSR build: pass 1, LDS-staged bucket scatter ----------------
__global__ __launch_bounds__(256) void k_bucket(const int* __restrict__ src,
                                                const int* __restrict__ dst,
                                                int* __restrict__ gcur,
                                                unsigned* __restrict__ pairs) {
  __shared__ int sd[4096];
  __shared__ int ss[4096];
  __shared__ int sh[NBUK];     // hist
  __shared__ int sexcl[NBUK];  // block-local exclusive offset
  __shared__ int scur[NBUK];   // running cursor
  __shared__ int sbase[NBUK];  // global base within bucket region
  __shared__ int wsum[4];
  const int tid = threadIdx.x;
  const int i0 = blockIdx.x * 4096;
  #pragma unroll
  for (int j = 0; j < 16; ++j) {
    int e = i0 + j * 256 + tid;
    sd[j * 256 + tid] = (e < NE) ? __builtin_nontemporal_load(dst + e) : -1;
    ss[j * 256 + tid] = (e < NE) ? __builtin_nontemporal_load(src + e) : 0;
  }
  if (tid < NBUK) sh[tid] = 0;
  __syncthreads();
  #pragma unroll
  for (int j = 0; j < 16; ++j) {
    int d = sd[j * 256 + tid];
    if (d >= 0) atomicAdd(&sh[d >> 9], 1);
  }
  __syncthreads();
  // scan 256 (valid < NBUK)
  {
    int v = (tid < NBUK) ? sh[tid] : 0;
    int lane = tid & 63, w = tid >> 6;
    int incl = v;
    #pragma unroll
    for (int o = 1; o < 64; o <<= 1) {
      int u = __shfl_up(incl, o);
      if (lane >= o) incl += u;
    }
    if (lane == 63) wsum[w] = incl;
    __syncthreads();
    int off = 0;
    for (int k = 0; k < w; ++k) off += wsum[k];
    if (tid < NBUK) {
      int ex = off + incl - v;
      sexcl[tid] = ex;
      scur[tid] = ex;
      sbase[tid] = (v > 0) ? atomicAdd(&gcur[tid], v) : 0;
    }
  }
  __syncthreads();
  #pragma unroll
  for (int j = 0; j < 16; ++j) {
    int d = sd[j * 256 + tid];
    if (d >= 0) {
      int b = d >> 9;
      int lp = atomicAdd(&scur[b], 1);
      unsigned pk = ((unsigned)(d & 511) << 17) | (unsigned)ss[j * 256 + tid];
      pairs[(size_t)b * BCAP + sbase[b] + (lp - sexcl[b])] = pk;
    }
  }
}

// pass 1b: exclusive scan of bucket counts -> bucket_base
__global__ __launch_bounds__(256) void k_bscan(const int* __restrict__ gcur,
                                               int* __restrict__ bucket_base,
                                               int* __restrict__ row_ptr) {
  __shared__ int wsum[4];
  const int tid = threadIdx.x;
  int v = (tid < NBUK) ? gcur[tid] : 0;
  int lane = tid & 63, w = tid >> 6;
  int incl = v;
  #pragma unroll
  for (int o = 1; o < 64; o <<= 1) {
    int u = __shfl_up(incl, o);
    if (lane >= o) incl += u;
  }
  if (lane == 63) wsum[w] = incl;
  __syncthreads();
  int off = 0;
  for (int k = 0; k < w; ++k) off += wsum[k];
  if (tid < NBUK) bucket_base[tid] = off + incl - v;
  if (tid == 0) row_ptr[NN] = NE;
}

// pass 2: per-bucket local CSR in LDS, localized writes
__global__ __launch_bounds__(256) void k_pass2(const unsigned* __restrict__ pairs,
                                               const int* __restrict__ gcur,
                                               const int* __restrict__ bucket_base,
                                               int* __restrict__ row_ptr,
                                               int* __restrict__ col_idx) {
  __shared__ unsigned spk[BCAP];
  __shared__ int h[512];
  __shared__ int cur[512];
  __shared__ int wsum[4];
  const int b = blockIdx.x;
  const int tid = threadIdx.x;
  const int cnt = gcur[b];
  const int base = bucket_base[b];
  for (int i = tid; i < cnt; i += 256) spk[i] = pairs[(size_t)b * BCAP + i];
  h[tid] = 0; h[tid + 256] = 0;
  __syncthreads();
  for (int i = tid; i < cnt; i += 256) atomicAdd(&h[spk[i] >> 17], 1);
  __syncthreads();
  // scan 512 with 2 per thread
  int c0 = h[2 * tid], c1 = h[2 * tid + 1];
  {
    int v = c0 + c1;
    int lane = tid & 63, w = tid >> 6;
    int incl = v;
    #pragma unroll
    for (int o = 1; o < 64; o <<= 1) {
      int u = __shfl_up(incl, o);
      if (lane >= o) incl += u;
    }
    if (lane == 63) wsum[w] = incl;
    __syncthreads();
    int off = 0;
    for (int k = 0; k < w; ++k) off += wsum[k];
    int e0 = off + incl - v;
    int e1 = e0 + c0;
    int node0 = b * 512 + 2 * tid;
    if (node0 < NN) row_ptr[node0] = base + e0;
    if (node0 + 1 < NN) row_ptr[node0 + 1] = base + e1;
    cur[2 * tid] = e0;
    cur[2 * tid + 1] = e1;
  }
  __syncthreads();
  for (int i = tid; i < cnt; i += 256) {
    unsigned pk = spk[i];
    int dl = pk >> 17;
    int p = atomicAdd(&cur[dl], 1);
    col_idx[base + p] = (int)(pk & 0x1FFFFu);
  }
}

// ---------------- merged weight/bias prep ----------------
struct PrepArgs {
  const float* W[9];
  const float* g[9];
  const float* rv[9];
  unsigned short* out[9];
  int k0[9];
  int K[9];
  const float* ba[4];
  const float* gg[4];
  const float* be[4];
  const float* rm[4];
  const float* rvv[4];
  float* bout;
};

__global__ __launch_bounds__(256) void k_prep(PrepArgs a) {
  int id = blockIdx.x * 256 + threadIdx.x;
  if (id < 9 * 16384) {
    int chunk = id >> 14;
    int r = id & 16383;
    int kk = r >> 7;
    int n = r & 127;
    float s = a.g[chunk] ? a.g[chunk][n] * rsqrtf(a.rv[chunk][n] + BN_EPS) : 1.f;
    int kg = a.k0[chunk] + kk;
    float v = (kg < a.K[chunk]) ? a.W[chunk][(size_t)kg * HD + n] * s : 0.f;
    unsigned short hb = f2bf(v);
    unsigned short lb = f2bf(v - bf2f(hb));
    int idx = n * 128 + (kk ^ ((n & 7) << 3));
    a.out[chunk][idx] = hb;
    a.out[chunk][16384 + idx] = lb;
  } else {
    int t = id - 9 * 16384;
    if (t < 512) {
      int l = t >> 7, c = t & 127;
      float s = a.gg[l][c] * rsqrtf(a.rvv[l][c] + BN_EPS);
      a.bout[l * 128 + c] = a.ba[l][c] * s + a.be[l][c] - a.rm[l][c] * s;
    }
  }
}

// ---------------- GEMM1: f32 A (x) bf16x3 split @ [K x 128] -> bf16 out ----------------
__global__ __launch_bounds__(256) void k_mgemm1(const float* __restrict__ A,
                                                const unsigned short* __restrict__ Wz,
                                                unsigned short* __restrict__ out,
                                                int K, int nchunks) {
  __shared__ unsigned short sW[32768];
  const int tid = threadIdx.x;
  const int wv = tid >> 6, ln = tid & 63;
  const int l15 = ln & 15, l4 = ln >> 4;
  const int m0 = blockIdx.x * 128 + wv * 32;
  f32x4 acc[2][8] = {};
  const int sw = (l15 & 7) << 3;
  int kofs[4];
  #pragma unroll
  for (int ks = 0; ks < 4; ++ks) kofs[ks] = (((ks * 32 + l4 * 8) ^ sw)) + l15 * 128;

  for (int c = 0; c < nchunks; ++c) {
    {
      const ushort8* src = (const ushort8*)(Wz + (size_t)c * 32768);
      ushort8* dst = (ushort8*)sW;
      #pragma unroll
      for (int i = 0; i < 16; ++i) dst[tid + i * 256] = src[tid + i * 256];
    }
    __syncthreads();
    const int kc = c * 128;
    #pragma unroll
    for (int ks = 0; ks < 4; ++ks) {
      const int kbase = kc + ks * 32 + l4 * 8;
      const bool tail = (kc + ks * 32 + 32) > K;
      short8 ah[2], al[2];
      #pragma unroll
      for (int mf = 0; mf < 2; ++mf) {
        const int row = m0 + mf * 16 + l15;
        float v[8];
        if (row < NN && !tail) {
          const f32x2* ap = (const f32x2*)(A + (size_t)row * K + kbase);
          #pragma unroll
          for (int q = 0; q < 4; ++q) {
            f32x2 t = __builtin_nontemporal_load(ap + q);
            v[2 * q] = t[0]; v[2 * q + 1] = t[1];
          }
        } else if (row < NN) {
          #pragma unroll
          for (int j = 0; j < 8; ++j) {
            int k = kbase + j;
            v[j] = (k < K) ? A[(size_t)row * K + k] : 0.f;
          }
        } else {
          #pragma unroll
          for (int j = 0; j < 8; ++j) v[j] = 0.f;
        }
        #pragma unroll
        for (int j = 0; j < 8; ++j) {
          unsigned short hb = f2bf(v[j]);
          ah[mf][j] = (short)hb;
          al[mf][j] = (short)f2bf(v[j] - bf2f(hb));
        }
      }
      #pragma unroll
      for (int n = 0; n < 8; ++n) {
        const int idx = n * 2048 + kofs[ks];
        short8 bh = *(const short8*)&sW[idx];
        short8 bl = *(const short8*)&sW[idx + 16384];
        #pragma unroll
        for (int mf = 0; mf < 2; ++mf) {
          acc[mf][n] = __builtin_amdgcn_mfma_f32_16x16x32_bf16(BC(ah[mf]), BC(bh), acc[mf][n], 0, 0, 0);
          acc[mf][n] = __builtin_amdgcn_mfma_f32_16x16x32_bf16(BC(ah[mf]), BC(bl), acc[mf][n], 0, 0, 0);
          acc[mf][n] = __builtin_amdgcn_mfma_f32_16x16x32_bf16(BC(al[mf]), BC(bh), acc[mf][n], 0, 0, 0);
        }
      }
    }
    __syncthreads();
  }
  #pragma unroll
  for (int mf = 0; mf < 2; ++mf) {
    #pragma unroll
    for (int n = 0; n < 8; ++n) {
      const int col = n * 16 + l15;
      #pragma unroll
      for (int r = 0; r < 4; ++r) {
        const int row = m0 + mf * 16 + l4 * 4 + r;
        if (row < NN) out[(size_t)row * HD + col] = f2bf(acc[mf][n][r]);
      }
    }
  }
}

// ---------------- GEMM (single, layer-4 b): bf16 A @ (Wh+Wl) -> bf16 out ----------------
template <int BIAS, int RELU>
__global__ __launch_bounds__(256) void k_mgemmB(const unsigned short* __restrict__ A,
                                                const unsigned short* __restrict__ Wz,
                                                const float* __restrict__ bias,
                                                unsigned short* __restrict__ out) {
  __shared__ unsigned short sW[32768];
  const int tid = threadIdx.x;
  const int wv = tid >> 6, ln = tid & 63;
  const int l15 = ln & 15, l4 = ln >> 4;
  const int m0 = blockIdx.x * 128 + wv * 32;
  f32x4 acc[2][8] = {};
  const int sw = (l15 & 7) << 3;
  {
    const ushort8* src = (const ushort8*)Wz;
    ushort8* dst = (ushort8*)sW;
    #pragma unroll
    for (int i = 0; i < 16; ++i) dst[tid + i * 256] = src[tid + i * 256];
  }
  __syncthreads();
  #pragma unroll
  for (int ks = 0; ks < 4; ++ks) {
    const int kbase = ks * 32 + l4 * 8;
    short8 a[2];
    #pragma unroll
    for (int mf = 0; mf < 2; ++mf) {
      const int row = m0 + mf * 16 + l15;
      if (row < NN) a[mf] = *(const short8*)(A + (size_t)row * HD + kbase);
      else a[mf] = short8{0, 0, 0, 0, 0, 0, 0, 0};
    }
    const int kof = (kbase ^ sw) + l15 * 128;
    #pragma unroll
    for (int n = 0; n < 8; ++n) {
      const int idx = n * 2048 + kof;
      short8 bh = *(const short8*)&sW[idx];
      short8 bl = *(const short8*)&sW[idx + 16384];
      #pragma unroll
      for (int mf = 0; mf < 2; ++mf) {
        acc[mf][n] = __builtin_amdgcn_mfma_f32_16x16x32_bf16(BC(a[mf]), BC(bh), acc[mf][n], 0, 0, 0);
        acc[mf][n] = __builtin_amdgcn_mfma_f32_16x16x32_bf16(BC(a[mf]), BC(bl), acc[mf][n], 0, 0, 0);
      }
    }
  }
  #pragma unroll
  for (int mf = 0; mf < 2; ++mf) {
    #pragma unroll
    for (int n = 0; n < 8; ++n) {
      const int col = n * 16 + l15;
      float bv = BIAS ? bias[col] : 0.f;
      #pragma unroll
      for (int r = 0; r < 4; ++r) {
        const int row = m0 + mf * 16 + l4 * 4 + r;
        if (row < NN) {
          float o = acc[mf][n][r] + bv;
          if (RELU) o = fmaxf(o, 0.f);
          out[(size_t)row * HD + col] = f2bf(o);
        }
      }
    }
  }
}

// ---------------- fused Wb+Wa GEMM: Y = relu(H@Wb + bb) @ Wa, X stays in LDS ------
__global__ __launch_bounds__(256) void k_fused(const unsigned short* __restrict__ H,
                                               const unsigned short* __restrict__ Wzb,
                                               const float* __restrict__ bb,
                                               const unsigned short* __restrict__ Wza,
                                               unsigned short* __restrict__ Yout) {
  __shared__ unsigned short sB[16384];   // Wb N-half: hi[0:8192] lo[8192:16384]
  __shared__ unsigned short sA2[16384];  // Wa k-half: hi[0:8192] lo[8192:16384]
  __shared__ unsigned short sX[8192];    // X half-tile 128x64 swizzled
  const int tid = threadIdx.x;
  const int wv = tid >> 6, ln = tid & 63;
  const int l15 = ln & 15, l4 = ln >> 4;
  const int m0 = blockIdx.x * 128 + wv * 32;
  const int sw = (l15 & 7) << 3;
  f32x4 acc2[2][8] = {};

  // prologue: load all H A-fragments (held across both halves)
  short8 a[2][4];
  #pragma unroll
  for (int mf = 0; mf < 2; ++mf) {
    const int row = m0 + mf * 16 + l15;
    #pragma unroll
    for (int ks = 0; ks < 4; ++ks) {
      if (row < NN) a[mf][ks] = *(const short8*)(H + (size_t)row * HD + ks * 32 + l4 * 8);
      else a[mf][ks] = short8{0, 0, 0, 0, 0, 0, 0, 0};
    }
  }

  #pragma unroll 1
  for (int p = 0; p < 2; ++p) {
    // stage Wb N-half (cols p*64..+63): hi slab chunk + lo slab chunk
    {
      ushort8* d = (ushort8*)sB;
      const ushort8* s1 = (const ushort8*)(Wzb + p * 8192);
      const ushort8* s2 = (const ushort8*)(Wzb + 16384 + p * 8192);
      #pragma unroll
      for (int i = 0; i < 4; ++i) d[tid + i * 256] = s1[tid + i * 256];
      #pragma unroll
      for (int i = 0; i < 4; ++i) d[1024 + tid + i * 256] = s2[tid + i * 256];
    }
    // stage Wa k-half (rows p*64..+63, all 128 cols): per-n contiguous 64-blocks
    {
      ushort8* d2 = (ushort8*)sA2;
      const ushort8* sa = (const ushort8*)Wza;
      #pragma unroll
      for (int i = 0; i < 4; ++i) {
        int idx = tid + i * 256;          // 0..1023
        int n = idx >> 3, q8 = idx & 7;
        d2[idx] = sa[n * 16 + p * 8 + q8];
      }
      #pragma unroll
      for (int i = 0; i < 4; ++i) {
        int idx = tid + i * 256;
        int n = idx >> 3, q8 = idx & 7;
        d2[1024 + idx] = sa[2048 + n * 16 + p * 8 + q8];
      }
    }
    __syncthreads();

    // GEMM1 half: X[:, p-half] = H @ Wb[:, p-half]
    f32x4 acc1[2][4] = {};
    #pragma unroll
    for (int ks = 0; ks < 4; ++ks) {
      const int kof = (ks * 32 + l4 * 8) ^ sw;
      #pragma unroll
      for (int nf = 0; nf < 4; ++nf) {
        const int idx = (nf * 16 + l15) * 128 + kof;
        short8 bh = *(const short8*)&sB[idx];
        short8 bl = *(const short8*)&sB[8192 + idx];
        #pragma unroll
        for (int mf = 0; mf < 2; ++mf) {
          acc1[mf][nf] = __builtin_amdgcn_mfma_f32_16x16x32_bf16(BC(a[mf][ks]), BC(bh), acc1[mf][nf], 0, 0, 0);
          acc1[mf][nf] = __builtin_amdgcn_mfma_f32_16x16x32_bf16(BC(a[mf][ks]), BC(bl), acc1[mf][nf], 0, 0, 0);
        }
      }
    }
    // X epilogue -> swizzled LDS (wave-private rows, no barrier needed)
    #pragma unroll
    for (int mf = 0; mf < 2; ++mf) {
      #pragma unroll
      for (int nf = 0; nf < 4; ++nf) {
        const int colL = nf * 16 + l15;
        const float bv = bb[p * 64 + colL];
        #pragma unroll
        for (int r = 0; r < 4; ++r) {
          const int rowL = wv * 32 + mf * 16 + l4 * 4 + r;
          sX[rowL * 64 + (colL ^ ((rowL & 7) << 3))] = f2bf(fmaxf(acc1[mf][nf][r] + bv, 0.f));
        }
      }
    }
    // GEMM2 half: Y += X[:, p-half] @ Wa[p-half, :]
    #pragma unroll
    for (int ks2 = 0; ks2 < 2; ++ks2) {
      const int xkof = (ks2 * 32 + l4 * 8) ^ sw;
      short8 xf[2];
      #pragma unroll
      for (int mf = 0; mf < 2; ++mf) {
        const int rowL = wv * 32 + mf * 16 + l15;
        xf[mf] = *(const short8*)&sX[rowL * 64 + xkof];
      }
      #pragma unroll
      for (int nf = 0; nf < 8; ++nf) {
        const int idx = (nf * 16 + l15) * 64 + xkof;
        short8 wh = *(const short8*)&sA2[idx];
        short8 wl = *(const short8*)&sA2[8192 + idx];
        #pragma unroll
        for (int mf = 0; mf < 2; ++mf) {
          acc2[mf][nf] = __builtin_amdgcn_mfma_f32_16x16x32_bf16(BC(xf[mf]), BC(wh), acc2[mf][nf], 0, 0, 0);
          acc2[mf][nf] = __builtin_amdgcn_mfma_f32_16x16x32_bf16(BC(xf[mf]), BC(wl), acc2[mf][nf], 0, 0, 0);
        }
      }
    }
    __syncthreads();
  }
  // epilogue: Y (a-GEMM output: no bias/relu)
  #pragma unroll
  for (int mf = 0; mf < 2; ++mf) {
    #pragma unroll
    for (int n = 0; n < 8; ++n) {
      const int col = n * 16 + l15;
      #pragma unroll
      for (int r = 0; r < 4; ++r) {
        const int row = m0 + mf * 16 + l4 * 4 + r;
        if (row < NN) Yout[(size_t)row * HD + col] = f2bf(acc2[mf][n][r]);
      }
    }
  }
}

// ---------------- aggregation (bf16): 16 lanes/row, 4 rows/wave, x2 unroll ----------
__global__ __launch_bounds__(256) void k_agg(const unsigned short* __restrict__ y,
                                             const int* __restrict__ row_ptr,
                                             const int* __restrict__ col_idx,
                                             const float* __restrict__ bias,
                                             unsigned short* __restrict__ h) {
  const int node = blockIdx.x * 4 + (threadIdx.x >> 6);
  const int ln = threadIdx.x & 63;
  const int l15 = ln & 15, grp = ln >> 4;
  if (node >= NN) return;
  float acc[8] = {};
  const int beg = row_ptr[node], end = row_ptr[node + 1];
  int e = beg;
  for (; e + 8 <= end; e += 8) {
    const int s0 = __builtin_nontemporal_load(col_idx + e + grp);
    const int s1 = __builtin_nontemporal_load(col_idx + e + 4 + grp);
    const ushort8 v0 = *(const ushort8*)(y + (size_t)s0 * HD + l15 * 8);
    const ushort8 v1 = *(const ushort8*)(y + (size_t)s1 * HD + l15 * 8);
    #pragma unroll
    for (int j = 0; j < 8; ++j)
      acc[j] += bf2f((unsigned short)v0[j]) + bf2f((unsigned short)v1[j]);
  }
  if (e + 4 <= end) {
    const int s0 = __builtin_nontemporal_load(col_idx + e + grp);
    const ushort8 v0 = *(const ushort8*)(y + (size_t)s0 * HD + l15 * 8);
    #pragma unroll
    for (int j = 0; j < 8; ++j) acc[j] += bf2f((unsigned short)v0[j]);
    e += 4;
  }
  if (e + grp < end) {
    const int s0 = col_idx[e + grp];
    const ushort8 v0 = *(const ushort8*)(y + (size_t)s0 * HD + l15 * 8);
    #pragma unroll
    for (int j = 0; j < 8; ++j) acc[j] += bf2f((unsigned short)v0[j]);
  }
  #pragma unroll
  for (int j = 0; j < 8; ++j) {
    acc[j] += __shfl_xor(acc[j], 16);
    acc[j] += __shfl_xor(acc[j], 32);
  }
  const ushort8 sv = *(const ushort8*)(y + (size_t)node * HD + l15 * 8);
  const f32x4* b4 = (const f32x4*)(bias + l15 * 8);
  const f32x4 b0 = b4[0], b1 = b4[1];
  ushort8 o;
  #pragma unroll
  for (int j = 0; j < 8; ++j) {
    const float bj = (j < 4) ? b0[j] : b1[j - 4];
    o[j] = (unsigned short)f2bf(fmaxf(acc[j] + bf2f((unsigned short)sv[j]) + bj, 0.f));
  }
  if (grp == 0) *(ushort8*)(h + (size_t)node * HD + l15 * 8) = o;
}

// ---------------- pooling ----------------
__global__ __launch_bounds__(256) void k_pool2(const unsigned short* __restrict__ h,
                                               const int* __restrict__ batch,
                                               const float* __restrict__ Wl,
                                               float* __restrict__ sums,
                                               float* __restrict__ cnts) {
  __shared__ float sb[NG];
  __shared__ int sc[NG];
  const int tid = threadIdx.x;
  for (int i = tid; i < NG; i += 256) { sb[i] = 0.f; sc[i] = 0; }
  __syncthreads();
  const int wv = tid >> 6, ln = tid & 63;
  const float2 w2 = reinterpret_cast<const float2*>(Wl)[ln];
  #pragma unroll 1
  for (int i = 0; i < 16; ++i) {
    const int node = blockIdx.x * 64 + wv * 16 + i;
    if (node < NN) {
      const ushort2 hv = reinterpret_cast<const ushort2*>(h)[(size_t)node * 64 + ln];
      float d = bf2f(hv.x) * w2.x + bf2f(hv.y) * w2.y;
      #pragma unroll
      for (int off = 32; off > 0; off >>= 1) d += __shfl_down(d, off);
      if (ln == 0) {
        const int g = batch[node];
        atomicAdd(&sb[g], d);
        atomicAdd(&sc[g], 1);
      }
    }
  }
  __syncthreads();
  for (int i = tid; i < NG; i += 256)
    if (sc[i]) { atomicAdd(&sums[i], sb[i]); atomicAdd(&cnts[i], (float)sc[i]); }
}

__global__ void k_final(const float* __restrict__ sums, const float* __restrict__ cnts,
                        const float* __restrict__ bl, float* __restrict__ out) {
  int g = blockIdx.x * 256 + threadIdx.x;
  if (g < NG) out[g] = sums[g] / fmaxf(cnts[g], 1.f) + bl[0];
}

// ---------------- launch ----------------
extern "C" void kernel_launch(void* const* d_in, const int* in_sizes, int n_in,
                              void* d_out, int out_size, void* d_ws, size_t ws_size,
                              hipStream_t stream) {
  const float* x = (const float*)d_in[0];
  const int* edges = (const int*)d_in[1];
  const int* batch = (const int*)d_in[2];
  const int* e_src = edges;
  const int* e_dst = edges + NE;
  const float* Wl = (const float*)d_in[35];
  const float* bl = (const float*)d_in[36];
  float* out = (float*)d_out;
  auto P = [&](int l, int which) -> const float* {
    return (const float*)d_in[3 + (l - 1) * 8 + which];
  };

  char* ws = (char*)d_ws;
  size_t off = 0;
  auto take = [&](size_t bytes) -> void* {
    void* p = ws + off;
    off = (off + bytes + 255) & ~(size_t)255;
    return p;
  };
  unsigned short* Y = (unsigned short*)take((size_t)NN * HD * 2);
  unsigned short* H = (unsigned short*)take((size_t)NN * HD * 2);
  unsigned short* X = (unsigned short*)take((size_t)NN * HD * 2);
  int* row_ptr = (int*)take((size_t)(NN + 1) * 4);
  int* col_idx = (int*)take((size_t)NE * 4);
  unsigned* pairs = (unsigned*)take((size_t)NBUK * BCAP * 4);
  int* gcur = (int*)take((size_t)NBUK * 4);
  int* bucket_base = (int*)take((size_t)NBUK * 4);
  unsigned short* Wza[4];
  unsigned short* Wzb[4];
  Wza[0] = (unsigned short*)take((size_t)2 * 32768 * 2);
  for (int l = 1; l < 4; ++l) Wza[l] = (unsigned short*)take((size_t)32768 * 2);
  for (int l = 0; l < 4; ++l) Wzb[l] = (unsigned short*)take((size_t)32768 * 2);
  float* bf = (float*)take((size_t)4 * HD * 4);
  float* psum = (float*)take((size_t)NG * 4 * 2);
  float* pcnt = psum + NG;

  // CSR build (bucket sort)
  hipMemsetAsync(gcur, 0, (size_t)NBUK * 4, stream);
  k_bucket<<<(NE + 4095) / 4096, 256, 0, stream>>>(e_src, e_dst, gcur, pairs);
  k_bscan<<<1, 256, 0, stream>>>(gcur, bucket_base, row_ptr);
  k_pass2<<<NBUK, 256, 0, stream>>>(pairs, gcur, bucket_base, row_ptr, col_idx);

  // merged weight/bias prep
  PrepArgs pa;
  for (int c = 0; c < 9; ++c) {
    if (c < 2) { pa.W[c] = P(1, 0); pa.g[c] = P(1, 2); pa.rv[c] = P(1, 5);
                 pa.out[c] = Wza[0] + c * 32768; pa.k0[c] = c * 128; pa.K[c] = FIN; }
    else if (c < 5) { int l = c - 1; pa.W[c] = P(l + 1, 0); pa.g[c] = P(l + 1, 2);
                      pa.rv[c] = P(l + 1, 5); pa.out[c] = Wza[l]; pa.k0[c] = 0; pa.K[c] = HD; }
    else { int l = c - 5; pa.W[c] = P(l + 1, 6); pa.g[c] = nullptr; pa.rv[c] = nullptr;
           pa.out[c] = Wzb[l]; pa.k0[c] = 0; pa.K[c] = HD; }
  }
  for (int l = 0; l < 4; ++l) {
    pa.ba[l] = P(l + 1, 1); pa.gg[l] = P(l + 1, 2); pa.be[l] = P(l + 1, 3);
    pa.rm[l] = P(l + 1, 4); pa.rvv[l] = P(l + 1, 5);
  }
  pa.bout = bf;
  k_prep<<<(9 * 16384 + 512 + 255) / 256, 256, 0, stream>>>(pa);

  hipMemsetAsync(psum, 0, (size_t)NG * 8, stream);

  const int gemm_grid = (NN + 127) / 128;
  // y1 = x @ W1a'
  k_mgemm1<<<gemm_grid, 256, 0, stream>>>(x, Wza[0], Y, FIN, 2);
  for (int l = 1; l <= 3; ++l) {
    k_agg<<<NN / 4, 256, 0, stream>>>(Y, row_ptr, col_idx, bf + (l - 1) * HD, H);
    // Y_{l+1} = relu(H @ Wb + bb) @ W(l+1)a'  (X never materialized)
    k_fused<<<gemm_grid, 256, 0, stream>>>(H, Wzb[l - 1], P(l, 7), Wza[l], Y);
  }
  // layer 4
  k_agg<<<NN / 4, 256, 0, stream>>>(Y, row_ptr, col_idx, bf + 3 * HD, H);
  k_mgemmB<1, 1><<<gemm_grid, 256, 0, stream>>>(H, Wzb[3], P(4, 7), X);
  k_pool2<<<(NN + 63) / 64, 256, 0, stream>>>(X, batch, Wl, psum, pcnt);
  k_final<<<(NG + 255) / 256, 256, 0, stream>>>(psum, pcnt, bl, out);
}

// Round 6
// 521.990 us; speedup vs baseline: 3.6748x; 1.0216x over previous
//
#include <hip/hip_runtime.h>

#define NN 100000
#define NE 1600000
#define NG 512
#define FIN 226
#define HD 128
#define BN_EPS 1e-5f
#define NBUK 196        // ceil(NN/512)
#define BCAP 10016      // per-bucket pair capacity (mean 8163, sigma ~90)

typedef __attribute__((ext_vector_type(8))) __bf16 bf16x8;
typedef __attribute__((ext_vector_type(8))) short short8;
typedef __attribute__((ext_vector_type(8))) unsigned short ushort8;
typedef __attribute__((ext_vector_type(4))) float f32x4;
typedef __attribute__((ext_vector_type(2))) float f32x2;

#define BC(x) __builtin_bit_cast(bf16x8, x)

__device__ inline unsigned short f2bf(float v) {
  unsigned u = __builtin_bit_cast(unsigned, v);
  return (unsigned short)((u + 0x7FFFu + ((u >> 16) & 1u)) >> 16);
}
__device__ inline float bf2f(unsigned short b) {
  return __builtin_bit_cast(float, (unsigned)b << 16);
}

// ---------------- CSR build: pass 1, LDS-staged bucket scatter ----------------
__global__ __launch_bounds__(256) void k_bucket(const int* __restrict__ src,
                                                const int* __restrict__ dst,
                                                int* __restrict__ gcur,
                                                unsigned* __restrict__ pairs) {
  __shared__ int sd[4096];
  __shared__ int ss[4096];
  __shared__ int sh[NBUK];     // hist
  __shared__ int sexcl[NBUK];  // block-local exclusive offset
  __shared__ int scur[NBUK];   // running cursor
  __shared__ int sbase[NBUK];  // global base within bucket region
  __shared__ int wsum[4];
  const int tid = threadIdx.x;
  const int i0 = blockIdx.x * 4096;
  #pragma unroll
  for (int j = 0; j < 16; ++j) {
    int e = i0 + j * 256 + tid;
    sd[j * 256 + tid] = (e < NE) ? __builtin_nontemporal_load(dst + e) : -1;
    ss[j * 256 + tid] = (e < NE) ? __builtin_nontemporal_load(src + e) : 0;
  }
  if (tid < NBUK) sh[tid] = 0;
  __syncthreads();
  #pragma unroll
  for (int j = 0; j < 16; ++j) {
    int d = sd[j * 256 + tid];
    if (d >= 0) atomicAdd(&sh[d >> 9], 1);
  }
  __syncthreads();
  // scan 256 (valid < NBUK)
  {
    int v = (tid < NBUK) ? sh[tid] : 0;
    int lane = tid & 63, w = tid >> 6;
    int incl = v;
    #pragma unroll
    for (int o = 1; o < 64; o <<= 1) {
      int u = __shfl_up(incl, o);
      if (lane >= o) incl += u;
    }
    if (lane == 63) wsum[w] = incl;
    __syncthreads();
    int off = 0;
    for (int k = 0; k < w; ++k) off += wsum[k];
    if (tid < NBUK) {
      int ex = off + incl - v;
      sexcl[tid] = ex;
      scur[tid] = ex;
      sbase[tid] = (v > 0) ? atomicAdd(&gcur[tid], v) : 0;
    }
  }
  __syncthreads();
  #pragma unroll
  for (int j = 0; j < 16; ++j) {
    int d = sd[j * 256 + tid];
    if (d >= 0) {
      int b = d >> 9;
      int lp = atomicAdd(&scur[b], 1);
      unsigned pk = ((unsigned)(d & 511) << 17) | (unsigned)ss[j * 256 + tid];
      pairs[(size_t)b * BCAP + sbase[b] + (lp - sexcl[b])] = pk;
    }
  }
}

// pass 1b: exclusive scan of bucket counts -> bucket_base
__global__ __launch_bounds__(256) void k_bscan(const int* __restrict__ gcur,
                                               int* __restrict__ bucket_base,
                                               int* __restrict__ row_ptr) {
  __shared__ int wsum[4];
  const int tid = threadIdx.x;
  int v = (tid < NBUK) ? gcur[tid] : 0;
  int lane = tid & 63, w = tid >> 6;
  int incl = v;
  #pragma unroll
  for (int o = 1; o < 64; o <<= 1) {
    int u = __shfl_up(incl, o);
    if (lane >= o) incl += u;
  }
  if (lane == 63) wsum[w] = incl;
  __syncthreads();
  int off = 0;
  for (int k = 0; k < w; ++k) off += wsum[k];
  if (tid < NBUK) bucket_base[tid] = off + incl - v;
  if (tid == 0) row_ptr[NN] = NE;
}

// pass 2: per-bucket local CSR in LDS, localized writes
__global__ __launch_bounds__(256) void k_pass2(const unsigned* __restrict__ pairs,
                                               const int* __restrict__ gcur,
                                               const int* __restrict__ bucket_base,
                                               int* __restrict__ row_ptr,
                                               int* __restrict__ col_idx) {
  __shared__ unsigned spk[BCAP];
  __shared__ int h[512];
  __shared__ int cur[512];
  __shared__ int wsum[4];
  const int b = blockIdx.x;
  const int tid = threadIdx.x;
  const int cnt = gcur[b];
  const int base = bucket_base[b];
  for (int i = tid; i < cnt; i += 256) spk[i] = pairs[(size_t)b * BCAP + i];
  h[tid] = 0; h[tid + 256] = 0;
  __syncthreads();
  for (int i = tid; i < cnt; i += 256) atomicAdd(&h[spk[i] >> 17], 1);
  __syncthreads();
  // scan 512 with 2 per thread
  int c0 = h[2 * tid], c1 = h[2 * tid + 1];
  {
    int v = c0 + c1;
    int lane = tid & 63, w = tid >> 6;
    int incl = v;
    #pragma unroll
    for (int o = 1; o < 64; o <<= 1) {
      int u = __shfl_up(incl, o);
      if (lane >= o) incl += u;
    }
    if (lane == 63) wsum[w] = incl;
    __syncthreads();
    int off = 0;
    for (int k = 0; k < w; ++k) off += wsum[k];
    int e0 = off + incl - v;
    int e1 = e0 + c0;
    int node0 = b * 512 + 2 * tid;
    if (node0 < NN) row_ptr[node0] = base + e0;
    if (node0 + 1 < NN) row_ptr[node0 + 1] = base + e1;
    cur[2 * tid] = e0;
    cur[2 * tid + 1] = e1;
  }
  __syncthreads();
  for (int i = tid; i < cnt; i += 256) {
    unsigned pk = spk[i];
    int dl = pk >> 17;
    int p = atomicAdd(&cur[dl], 1);
    col_idx[base + p] = (int)(pk & 0x1FFFFu);
  }
}

// ---------------- merged weight/bias prep ----------------
struct PrepArgs {
  const float* W[9];
  const float* g[9];
  const float* rv[9];
  unsigned short* out[9];
  int k0[9];
  int K[9];
  const float* ba[4];
  const float* gg[4];
  const float* be[4];
  const float* rm[4];
  const float* rvv[4];
  float* bout;
};

__global__ __launch_bounds__(256) void k_prep(PrepArgs a) {
  int id = blockIdx.x * 256 + threadIdx.x;
  if (id < 9 * 16384) {
    int chunk = id >> 14;
    int r = id & 16383;
    int kk = r >> 7;
    int n = r & 127;
    float s = a.g[chunk] ? a.g[chunk][n] * rsqrtf(a.rv[chunk][n] + BN_EPS) : 1.f;
    int kg = a.k0[chunk] + kk;
    float v = (kg < a.K[chunk]) ? a.W[chunk][(size_t)kg * HD + n] * s : 0.f;
    unsigned short hb = f2bf(v);
    unsigned short lb = f2bf(v - bf2f(hb));
    int idx = n * 128 + (kk ^ ((n & 7) << 3));
    a.out[chunk][idx] = hb;
    a.out[chunk][16384 + idx] = lb;
  } else {
    int t = id - 9 * 16384;
    if (t < 512) {
      int l = t >> 7, c = t & 127;
      float s = a.gg[l][c] * rsqrtf(a.rvv[l][c] + BN_EPS);
      a.bout[l * 128 + c] = a.ba[l][c] * s + a.be[l][c] - a.rm[l][c] * s;
    }
  }
}

// ---------------- GEMM1: f32 A (x) bf16x3 split @ [K x 128] -> bf16 out ----------------
__global__ __launch_bounds__(256) void k_mgemm1(const float* __restrict__ A,
                                                const unsigned short* __restrict__ Wz,
                                                unsigned short* __restrict__ out,
                                                int K, int nchunks) {
  __shared__ unsigned short sW[32768];
  const int tid = threadIdx.x;
  const int wv = tid >> 6, ln = tid & 63;
  const int l15 = ln & 15, l4 = ln >> 4;
  const int m0 = blockIdx.x * 128 + wv * 32;
  f32x4 acc[2][8] = {};
  const int sw = (l15 & 7) << 3;
  int kofs[4];
  #pragma unroll
  for (int ks = 0; ks < 4; ++ks) kofs[ks] = (((ks * 32 + l4 * 8) ^ sw)) + l15 * 128;

  for (int c = 0; c < nchunks; ++c) {
    {
      const ushort8* src = (const ushort8*)(Wz + (size_t)c * 32768);
      ushort8* dst = (ushort8*)sW;
      #pragma unroll
      for (int i = 0; i < 16; ++i) dst[tid + i * 256] = src[tid + i * 256];
    }
    __syncthreads();
    const int kc = c * 128;
    #pragma unroll
    for (int ks = 0; ks < 4; ++ks) {
      const int kbase = kc + ks * 32 + l4 * 8;
      const bool tail = (kc + ks * 32 + 32) > K;
      short8 ah[2], al[2];
      #pragma unroll
      for (int mf = 0; mf < 2; ++mf) {
        const int row = m0 + mf * 16 + l15;
        float v[8];
        if (row < NN && !tail) {
          const f32x2* ap = (const f32x2*)(A + (size_t)row * K + kbase);
          #pragma unroll
          for (int q = 0; q < 4; ++q) {
            f32x2 t = __builtin_nontemporal_load(ap + q);
            v[2 * q] = t[0]; v[2 * q + 1] = t[1];
          }
        } else if (row < NN) {
          #pragma unroll
          for (int j = 0; j < 8; ++j) {
            int k = kbase + j;
            v[j] = (k < K) ? A[(size_t)row * K + k] : 0.f;
          }
        } else {
          #pragma unroll
          for (int j = 0; j < 8; ++j) v[j] = 0.f;
        }
        #pragma unroll
        for (int j = 0; j < 8; ++j) {
          unsigned short hb = f2bf(v[j]);
          ah[mf][j] = (short)hb;
          al[mf][j] = (short)f2bf(v[j] - bf2f(hb));
        }
      }
      #pragma unroll
      for (int n = 0; n < 8; ++n) {
        const int idx = n * 2048 + kofs[ks];
        short8 bh = *(const short8*)&sW[idx];
        short8 bl = *(const short8*)&sW[idx + 16384];
        #pragma unroll
        for (int mf = 0; mf < 2; ++mf) {
          acc[mf][n] = __builtin_amdgcn_mfma_f32_16x16x32_bf16(BC(ah[mf]), BC(bh), acc[mf][n], 0, 0, 0);
          acc[mf][n] = __builtin_amdgcn_mfma_f32_16x16x32_bf16(BC(ah[mf]), BC(bl), acc[mf][n], 0, 0, 0);
          acc[mf][n] = __builtin_amdgcn_mfma_f32_16x16x32_bf16(BC(al[mf]), BC(bh), acc[mf][n], 0, 0, 0);
        }
      }
    }
    __syncthreads();
  }
  #pragma unroll
  for (int mf = 0; mf < 2; ++mf) {
    #pragma unroll
    for (int n = 0; n < 8; ++n) {
      const int col = n * 16 + l15;
      #pragma unroll
      for (int r = 0; r < 4; ++r) {
        const int row = m0 + mf * 16 + l4 * 4 + r;
        if (row < NN) out[(size_t)row * HD + col] = f2bf(acc[mf][n][r]);
      }
    }
  }
}

// ---------------- GEMM (single, layer-4 b): bf16 A @ (Wh+Wl) -> bf16 out ----------------
template <int BIAS, int RELU>
__global__ __launch_bounds__(256) void k_mgemmB(const unsigned short* __restrict__ A,
                                                const unsigned short* __restrict__ Wz,
                                                const float* __restrict__ bias,
                                                unsigned short* __restrict__ out) {
  __shared__ unsigned short sW[32768];
  const int tid = threadIdx.x;
  const int wv = tid >> 6, ln = tid & 63;
  const int l15 = ln & 15, l4 = ln >> 4;
  const int m0 = blockIdx.x * 128 + wv * 32;
  f32x4 acc[2][8] = {};
  const int sw = (l15 & 7) << 3;
  {
    const ushort8* src = (const ushort8*)Wz;
    ushort8* dst = (ushort8*)sW;
    #pragma unroll
    for (int i = 0; i < 16; ++i) dst[tid + i * 256] = src[tid + i * 256];
  }
  __syncthreads();
  #pragma unroll
  for (int ks = 0; ks < 4; ++ks) {
    const int kbase = ks * 32 + l4 * 8;
    short8 a[2];
    #pragma unroll
    for (int mf = 0; mf < 2; ++mf) {
      const int row = m0 + mf * 16 + l15;
      if (row < NN) a[mf] = *(const short8*)(A + (size_t)row * HD + kbase);
      else a[mf] = short8{0, 0, 0, 0, 0, 0, 0, 0};
    }
    const int kof = (kbase ^ sw) + l15 * 128;
    #pragma unroll
    for (int n = 0; n < 8; ++n) {
      const int idx = n * 2048 + kof;
      short8 bh = *(const short8*)&sW[idx];
      short8 bl = *(const short8*)&sW[idx + 16384];
      #pragma unroll
      for (int mf = 0; mf < 2; ++mf) {
        acc[mf][n] = __builtin_amdgcn_mfma_f32_16x16x32_bf16(BC(a[mf]), BC(bh), acc[mf][n], 0, 0, 0);
        acc[mf][n] = __builtin_amdgcn_mfma_f32_16x16x32_bf16(BC(a[mf]), BC(bl), acc[mf][n], 0, 0, 0);
      }
    }
  }
  #pragma unroll
  for (int mf = 0; mf < 2; ++mf) {
    #pragma unroll
    for (int n = 0; n < 8; ++n) {
      const int col = n * 16 + l15;
      float bv = BIAS ? bias[col] : 0.f;
      #pragma unroll
      for (int r = 0; r < 4; ++r) {
        const int row = m0 + mf * 16 + l4 * 4 + r;
        if (row < NN) {
          float o = acc[mf][n][r] + bv;
          if (RELU) o = fmaxf(o, 0.f);
          out[(size_t)row * HD + col] = f2bf(o);
        }
      }
    }
  }
}

// ---------------- fused Wb+Wa GEMM: Y = relu(H@Wb + bb) @ Wa, X stays in LDS ------
__global__ __launch_bounds__(256) void k_fused(const unsigned short* __restrict__ H,
                                               const unsigned short* __restrict__ Wzb,
                                               const float* __restrict__ bb,
                                               const unsigned short* __restrict__ Wza,
                                               unsigned short* __restrict__ Yout) {
  __shared__ unsigned short sB[16384];   // Wb N-half: hi[0:8192] lo[8192:16384]
  __shared__ unsigned short sA2[16384];  // Wa k-half: hi[0:8192] lo[8192:16384]
  __shared__ unsigned short sX[8192];    // X half-tile 128x64 swizzled
  const int tid = threadIdx.x;
  const int wv = tid >> 6, ln = tid & 63;
  const int l15 = ln & 15, l4 = ln >> 4;
  const int m0 = blockIdx.x * 128 + wv * 32;
  const int sw = (l15 & 7) << 3;
  f32x4 acc2[2][8] = {};

  // prologue: load all H A-fragments (held across both halves)
  short8 a[2][4];
  #pragma unroll
  for (int mf = 0; mf < 2; ++mf) {
    const int row = m0 + mf * 16 + l15;
    #pragma unroll
    for (int ks = 0; ks < 4; ++ks) {
      if (row < NN) a[mf][ks] = *(const short8*)(H + (size_t)row * HD + ks * 32 + l4 * 8);
      else a[mf][ks] = short8{0, 0, 0, 0, 0, 0, 0, 0};
    }
  }

  #pragma unroll 1
  for (int p = 0; p < 2; ++p) {
    // stage Wb N-half (cols p*64..+63): hi slab chunk + lo slab chunk
    {
      ushort8* d = (ushort8*)sB;
      const ushort8* s1 = (const ushort8*)(Wzb + p * 8192);
      const ushort8* s2 = (const ushort8*)(Wzb + 16384 + p * 8192);
      #pragma unroll
      for (int i = 0; i < 4; ++i) d[tid + i * 256] = s1[tid + i * 256];
      #pragma unroll
      for (int i = 0; i < 4; ++i) d[1024 + tid + i * 256] = s2[tid + i * 256];
    }
    // stage Wa k-half (rows p*64..+63, all 128 cols): per-n contiguous 64-blocks
    {
      ushort8* d2 = (ushort8*)sA2;
      const ushort8* sa = (const ushort8*)Wza;
      #pragma unroll
      for (int i = 0; i < 4; ++i) {
        int idx = tid + i * 256;          // 0..1023
        int n = idx >> 3, q8 = idx & 7;
        d2[idx] = sa[n * 16 + p * 8 + q8];
      }
      #pragma unroll
      for (int i = 0; i < 4; ++i) {
        int idx = tid + i * 256;
        int n = idx >> 3, q8 = idx & 7;
        d2[1024 + idx] = sa[2048 + n * 16 + p * 8 + q8];
      }
    }
    __syncthreads();

    // GEMM1 half: X[:, p-half] = H @ Wb[:, p-half]
    f32x4 acc1[2][4] = {};
    #pragma unroll
    for (int ks = 0; ks < 4; ++ks) {
      const int kof = (ks * 32 + l4 * 8) ^ sw;
      #pragma unroll
      for (int nf = 0; nf < 4; ++nf) {
        const int idx = (nf * 16 + l15) * 128 + kof;
        short8 bh = *(const short8*)&sB[idx];
        short8 bl = *(const short8*)&sB[8192 + idx];
        #pragma unroll
        for (int mf = 0; mf < 2; ++mf) {
          acc1[mf][nf] = __builtin_amdgcn_mfma_f32_16x16x32_bf16(BC(a[mf][ks]), BC(bh), acc1[mf][nf], 0, 0, 0);
          acc1[mf][nf] = __builtin_amdgcn_mfma_f32_16x16x32_bf16(BC(a[mf][ks]), BC(bl), acc1[mf][nf], 0, 0, 0);
        }
      }
    }
    // X epilogue -> swizzled LDS (wave-private rows, no barrier needed)
    #pragma unroll
    for (int mf = 0; mf < 2; ++mf) {
      #pragma unroll
      for (int nf = 0; nf < 4; ++nf) {
        const int colL = nf * 16 + l15;
        const float bv = bb[p * 64 + colL];
        #pragma unroll
        for (int r = 0; r < 4; ++r) {
          const int rowL = wv * 32 + mf * 16 + l4 * 4 + r;
          sX[rowL * 64 + (colL ^ ((rowL & 7) << 3))] = f2bf(fmaxf(acc1[mf][nf][r] + bv, 0.f));
        }
      }
    }
    // GEMM2 half: Y += X[:, p-half] @ Wa[p-half, :]
    #pragma unroll
    for (int ks2 = 0; ks2 < 2; ++ks2) {
      const int xkof = (ks2 * 32 + l4 * 8) ^ sw;
      short8 xf[2];
      #pragma unroll
      for (int mf = 0; mf < 2; ++mf) {
        const int rowL = wv * 32 + mf * 16 + l15;
        xf[mf] = *(const short8*)&sX[rowL * 64 + xkof];
      }
      #pragma unroll
      for (int nf = 0; nf < 8; ++nf) {
        const int idx = (nf * 16 + l15) * 64 + xkof;
        short8 wh = *(const short8*)&sA2[idx];
        short8 wl = *(const short8*)&sA2[8192 + idx];
        #pragma unroll
        for (int mf = 0; mf < 2; ++mf) {
          acc2[mf][nf] = __builtin_amdgcn_mfma_f32_16x16x32_bf16(BC(xf[mf]), BC(wh), acc2[mf][nf], 0, 0, 0);
          acc2[mf][nf] = __builtin_amdgcn_mfma_f32_16x16x32_bf16(BC(xf[mf]), BC(wl), acc2[mf][nf], 0, 0, 0);
        }
      }
    }
    __syncthreads();
  }
  // epilogue: Y (a-GEMM output: no bias/relu)
  #pragma unroll
  for (int mf = 0; mf < 2; ++mf) {
    #pragma unroll
    for (int n = 0; n < 8; ++n) {
      const int col = n * 16 + l15;
      #pragma unroll
      for (int r = 0; r < 4; ++r) {
        const int row = m0 + mf * 16 + l4 * 4 + r;
        if (row < NN) Yout[(size_t)row * HD + col] = f2bf(acc2[mf][n][r]);
      }
    }
  }
}

// ---------------- aggregation (bf16): 16 lanes/row, 4 rows/wave, 16 rows in flight ----
__global__ __launch_bounds__(256) void k_agg(const unsigned short* __restrict__ y,
                                             const int* __restrict__ row_ptr,
                                             const int* __restrict__ col_idx,
                                             const float* __restrict__ bias,
                                             unsigned short* __restrict__ h) {
  const int node = blockIdx.x * 4 + (threadIdx.x >> 6);
  const int ln = threadIdx.x & 63;
  const int l15 = ln & 15, grp = ln >> 4;
  if (node >= NN) return;
  float acc[8] = {};
  const int beg = row_ptr[node], end = row_ptr[node + 1];
  int e = beg;
  // 16 edges per iteration: 4 per 16-lane group -> 16 x 256B rows in flight per wave
  for (; e + 16 <= end; e += 16) {
    const int s0 = __builtin_nontemporal_load(col_idx + e + grp);
    const int s1 = __builtin_nontemporal_load(col_idx + e + 4 + grp);
    const int s2 = __builtin_nontemporal_load(col_idx + e + 8 + grp);
    const int s3 = __builtin_nontemporal_load(col_idx + e + 12 + grp);
    const ushort8 v0 = *(const ushort8*)(y + (size_t)s0 * HD + l15 * 8);
    const ushort8 v1 = *(const ushort8*)(y + (size_t)s1 * HD + l15 * 8);
    const ushort8 v2 = *(const ushort8*)(y + (size_t)s2 * HD + l15 * 8);
    const ushort8 v3 = *(const ushort8*)(y + (size_t)s3 * HD + l15 * 8);
    #pragma unroll
    for (int j = 0; j < 8; ++j)
      acc[j] += (bf2f((unsigned short)v0[j]) + bf2f((unsigned short)v1[j])) +
                (bf2f((unsigned short)v2[j]) + bf2f((unsigned short)v3[j]));
  }
  for (; e + 8 <= end; e += 8) {
    const int s0 = __builtin_nontemporal_load(col_idx + e + grp);
    const int s1 = __builtin_nontemporal_load(col_idx + e + 4 + grp);
    const ushort8 v0 = *(const ushort8*)(y + (size_t)s0 * HD + l15 * 8);
    const ushort8 v1 = *(const ushort8*)(y + (size_t)s1 * HD + l15 * 8);
    #pragma unroll
    for (int j = 0; j < 8; ++j)
      acc[j] += bf2f((unsigned short)v0[j]) + bf2f((unsigned short)v1[j]);
  }
  if (e + 4 <= end) {
    const int s0 = __builtin_nontemporal_load(col_idx + e + grp);
    const ushort8 v0 = *(const ushort8*)(y + (size_t)s0 * HD + l15 * 8);
    #pragma unroll
    for (int j = 0; j < 8; ++j) acc[j] += bf2f((unsigned short)v0[j]);
    e += 4;
  }
  if (e + grp < end) {
    const int s0 = col_idx[e + grp];
    const ushort8 v0 = *(const ushort8*)(y + (size_t)s0 * HD + l15 * 8);
    #pragma unroll
    for (int j = 0; j < 8; ++j) acc[j] += bf2f((unsigned short)v0[j]);
  }
  #pragma unroll
  for (int j = 0; j < 8; ++j) {
    acc[j] += __shfl_xor(acc[j], 16);
    acc[j] += __shfl_xor(acc[j], 32);
  }
  const ushort8 sv = *(const ushort8*)(y + (size_t)node * HD + l15 * 8);
  const f32x4* b4 = (const f32x4*)(bias + l15 * 8);
  const f32x4 b0 = b4[0], b1 = b4[1];
  ushort8 o;
  #pragma unroll
  for (int j = 0; j < 8; ++j) {
    const float bj = (j < 4) ? b0[j] : b1[j - 4];
    o[j] = (unsigned short)f2bf(fmaxf(acc[j] + bf2f((unsigned short)sv[j]) + bj, 0.f));
  }
  if (grp == 0) *(ushort8*)(h + (size_t)node * HD + l15 * 8) = o;
}

// ---------------- pooling ----------------
__global__ __launch_bounds__(256) void k_pool2(const unsigned short* __restrict__ h,
                                               const int* __restrict__ batch,
                                               const float* __restrict__ Wl,
                                               float* __restrict__ sums,
                                               float* __restrict__ cnts) {
  __shared__ float sb[NG];
  __shared__ int sc[NG];
  const int tid = threadIdx.x;
  for (int i = tid; i < NG; i += 256) { sb[i] = 0.f; sc[i] = 0; }
  __syncthreads();
  const int wv = tid >> 6, ln = tid & 63;
  const float2 w2 = reinterpret_cast<const float2*>(Wl)[ln];
  #pragma unroll 1
  for (int i = 0; i < 16; ++i) {
    const int node = blockIdx.x * 64 + wv * 16 + i;
    if (node < NN) {
      const ushort2 hv = reinterpret_cast<const ushort2*>(h)[(size_t)node * 64 + ln];
      float d = bf2f(hv.x) * w2.x + bf2f(hv.y) * w2.y;
      #pragma unroll
      for (int off = 32; off > 0; off >>= 1) d += __shfl_down(d, off);
      if (ln == 0) {
        const int g = batch[node];
        atomicAdd(&sb[g], d);
        atomicAdd(&sc[g], 1);
      }
    }
  }
  __syncthreads();
  for (int i = tid; i < NG; i += 256)
    if (sc[i]) { atomicAdd(&sums[i], sb[i]); atomicAdd(&cnts[i], (float)sc[i]); }
}

__global__ void k_final(const float* __restrict__ sums, const float* __restrict__ cnts,
                        const float* __restrict__ bl, float* __restrict__ out) {
  int g = blockIdx.x * 256 + threadIdx.x;
  if (g < NG) out[g] = sums[g] / fmaxf(cnts[g], 1.f) + bl[0];
}

// ---------------- launch ----------------
extern "C" void kernel_launch(void* const* d_in, const int* in_sizes, int n_in,
                              void* d_out, int out_size, void* d_ws, size_t ws_size,
                              hipStream_t stream) {
  const float* x = (const float*)d_in[0];
  const int* edges = (const int*)d_in[1];
  const int* batch = (const int*)d_in[2];
  const int* e_src = edges;
  const int* e_dst = edges + NE;
  const float* Wl = (const float*)d_in[35];
  const float* bl = (const float*)d_in[36];
  float* out = (float*)d_out;
  auto P = [&](int l, int which) -> const float* {
    return (const float*)d_in[3 + (l - 1) * 8 + which];
  };

  char* ws = (char*)d_ws;
  size_t off = 0;
  auto take = [&](size_t bytes) -> void* {
    void* p = ws + off;
    off = (off + bytes + 255) & ~(size_t)255;
    return p;
  };
  unsigned short* Y = (unsigned short*)take((size_t)NN * HD * 2);
  unsigned short* H = (unsigned short*)take((size_t)NN * HD * 2);
  unsigned short* X = (unsigned short*)take((size_t)NN * HD * 2);
  int* row_ptr = (int*)take((size_t)(NN + 1) * 4);
  int* col_idx = (int*)take((size_t)NE * 4);
  unsigned* pairs = (unsigned*)take((size_t)NBUK * BCAP * 4);
  int* gcur = (int*)take((size_t)NBUK * 4);
  int* bucket_base = (int*)take((size_t)NBUK * 4);
  unsigned short* Wza[4];
  unsigned short* Wzb[4];
  Wza[0] = (unsigned short*)take((size_t)2 * 32768 * 2);
  for (int l = 1; l < 4; ++l) Wza[l] = (unsigned short*)take((size_t)32768 * 2);
  for (int l = 0; l < 4; ++l) Wzb[l] = (unsigned short*)take((size_t)32768 * 2);
  float* bf = (float*)take((size_t)4 * HD * 4);
  float* psum = (float*)take((size_t)NG * 4 * 2);
  float* pcnt = psum + NG;

  // CSR build (bucket sort)
  hipMemsetAsync(gcur, 0, (size_t)NBUK * 4, stream);
  k_bucket<<<(NE + 4095) / 4096, 256, 0, stream>>>(e_src, e_dst, gcur, pairs);
  k_bscan<<<1, 256, 0, stream>>>(gcur, bucket_base, row_ptr);
  k_pass2<<<NBUK, 256, 0, stream>>>(pairs, gcur, bucket_base, row_ptr, col_idx);

  // merged weight/bias prep
  PrepArgs pa;
  for (int c = 0; c < 9; ++c) {
    if (c < 2) { pa.W[c] = P(1, 0); pa.g[c] = P(1, 2); pa.rv[c] = P(1, 5);
                 pa.out[c] = Wza[0] + c * 32768; pa.k0[c] = c * 128; pa.K[c] = FIN; }
    else if (c < 5) { int l = c - 1; pa.W[c] = P(l + 1, 0); pa.g[c] = P(l + 1, 2);
                      pa.rv[c] = P(l + 1, 5); pa.out[c] = Wza[l]; pa.k0[c] = 0; pa.K[c] = HD; }
    else { int l = c - 5; pa.W[c] = P(l + 1, 6); pa.g[c] = nullptr; pa.rv[c] = nullptr;
           pa.out[c] = Wzb[l]; pa.k0[c] = 0; pa.K[c] = HD; }
  }
  for (int l = 0; l < 4; ++l) {
    pa.ba[l] = P(l + 1, 1); pa.gg[l] = P(l + 1, 2); pa.be[l] = P(l + 1, 3);
    pa.rm[l] = P(l + 1, 4); pa.rvv[l] = P(l + 1, 5);
  }
  pa.bout = bf;
  k_prep<<<(9 * 16384 + 512 + 255) / 256, 256, 0, stream>>>(pa);

  hipMemsetAsync(psum, 0, (size_t)NG * 8, stream);

  const int gemm_grid = (NN + 127) / 128;
  // y1 = x @ W1a'
  k_mgemm1<<<gemm_grid, 256, 0, stream>>>(x, Wza[0], Y, FIN, 2);
  for (int l = 1; l <= 3; ++l) {
    k_agg<<<NN / 4, 256, 0, stream>>>(Y, row_ptr, col_idx, bf + (l - 1) * HD, H);
    // Y_{l+1} = relu(H @ Wb + bb) @ W(l+1)a'  (X never materialized)
    k_fused<<<gemm_grid, 256, 0, stream>>>(H, Wzb[l - 1], P(l, 7), Wza[l], Y);
  }
  // layer 4
  k_agg<<<NN / 4, 256, 0, stream>>>(Y, row_ptr, col_idx, bf + 3 * HD, H);
  k_mgemmB<1, 1><<<gemm_grid, 256, 0, stream>>>(H, Wzb[3], P(4, 7), X);
  k_pool2<<<(NN + 63) / 64, 256, 0, stream>>>(X, batch, Wl, psum, pcnt);
  k_final<<<(NG + 255) / 256, 256, 0, stream>>>(psum, pcnt, bl, out);
}